// Round 4
// baseline (455.706 us; speedup 1.0000x reference)
//
#include <hip/hip_runtime.h>
#include <math.h>

#define TSEQ 2048
#define BATCH 4
#define NH 16
#define DH 64
#define DM 1024
#define NREL 129
#define NEGBIG (-1.0e30f)
#define FIXMAX 8.0f

typedef unsigned short u16;
typedef unsigned int u32;
typedef __attribute__((ext_vector_type(8))) short bf16x8;
typedef __attribute__((ext_vector_type(4))) float f32x4;
typedef __attribute__((ext_vector_type(4))) unsigned short u16x4;

typedef __attribute__((address_space(3))) void lds_void;
typedef const __attribute__((address_space(1))) void g_void;

__device__ inline u16 f2b(float f) {
    union { float f; u32 i; } c; c.f = f;
    u32 x = c.i;
    return (u16)((x + 0x7fffu + ((x >> 16) & 1u)) >> 16);
}

__global__ __launch_bounds__(256) void fill_kernel(float* __restrict__ out, int n, float v) {
    for (int i = blockIdx.x * 256 + threadIdx.x; i < n; i += gridDim.x * 256)
        out[i] = v;
}

// ---------------- LayerNorm: fp32 in -> bf16 out, one block per row ----------------
__global__ __launch_bounds__(256) void ln_kernel(const float* __restrict__ x,
        const float* __restrict__ gamma, const float* __restrict__ beta,
        u16* __restrict__ xn) {
    const int row = blockIdx.x;
    const int tid = threadIdx.x;
    const float* xr = x + (size_t)row * DM;
    f32x4 xv = *(const f32x4*)(xr + tid * 4);
    float s = xv.x + xv.y + xv.z + xv.w;
    float s2 = xv.x*xv.x + xv.y*xv.y + xv.z*xv.z + xv.w*xv.w;
#pragma unroll
    for (int off = 32; off > 0; off >>= 1) {
        s  += __shfl_down(s, off, 64);
        s2 += __shfl_down(s2, off, 64);
    }
    __shared__ alignas(16) float red[8];
    const int wv = tid >> 6, ln = tid & 63;
    if (ln == 0) { red[wv] = s; red[4 + wv] = s2; }
    __syncthreads();
    s  = red[0] + red[1] + red[2] + red[3];
    s2 = red[4] + red[5] + red[6] + red[7];
    const float mu = s * (1.0f / DM);
    float var = s2 * (1.0f / DM) - mu * mu;
    var = var > 0.0f ? var : 0.0f;
    const float rstd = rsqrtf(var + 1e-5f);
    f32x4 gv = *(const f32x4*)(gamma + tid * 4);
    f32x4 bv = *(const f32x4*)(beta + tid * 4);
    u16x4 ov;
    ov.x = f2b((xv.x - mu) * rstd * gv.x + bv.x);
    ov.y = f2b((xv.y - mu) * rstd * gv.y + bv.y);
    ov.z = f2b((xv.z - mu) * rstd * gv.z + bv.z);
    ov.w = f2b((xv.w - mu) * rstd * gv.w + bv.w);
    *(u16x4*)(xn + (size_t)row * DM + tid * 4) = ov;
}

// ---------------- Weight conversion: fp32 -> bf16, done ONCE ----------------
__global__ __launch_bounds__(256) void cvt3_kernel(const float* __restrict__ a,
        const float* __restrict__ b, const float* __restrict__ c,
        u16* __restrict__ dst) {
    const int i = blockIdx.x * 256 + threadIdx.x;      // vec4 index, [0, 3*2^18)
    const int m = i >> 18;                              // 2^18 vec4 per 1024x1024
    const int j = i & 0x3FFFF;
    const float* src = m == 0 ? a : (m == 1 ? b : c);
    const float scale = m == 0 ? 0.125f : 1.0f;
    f32x4 v = *(const f32x4*)(src + (size_t)j * 4);
    u16x4 o;
    o.x = f2b(v.x * scale); o.y = f2b(v.y * scale);
    o.z = f2b(v.z * scale); o.w = f2b(v.w * scale);
    *(u16x4*)(dst + (size_t)i * 4) = o;
}

__global__ __launch_bounds__(256) void cvt1_kernel(const float* __restrict__ src,
        u16* __restrict__ dst, int n4) {
    const int i = blockIdx.x * 256 + threadIdx.x;
    if (i >= n4) return;
    f32x4 v = *(const f32x4*)(src + (size_t)i * 4);
    u16x4 o;
    o.x = f2b(v.x); o.y = f2b(v.y); o.z = f2b(v.z); o.w = f2b(v.w);
    *(u16x4*)(dst + (size_t)i * 4) = o;
}

// ---------------- GEMM (m97 structure): 128x128 tile, BK=32 ----------------
#define BM 128
#define BN 128
#define BK 32

// Fused QKV projection: A(8192,1024)bf16 @ W3(3x1024,1024)bf16^T.
// XCD-locality remap: consecutive flat block ids round-robin across the 8 XCDs,
// so give each XCD 8 fixed m-panels (A tiles 8x256KB = 2MB, L2-resident) and
// stream the W panels. Without this, A is re-read 24x over the cross-XCD
// fabric (~770 MB -> the round-3 fabric bound).
__global__ __launch_bounds__(256) void gemm_qkv(const u16* __restrict__ A,
        const u16* __restrict__ W3, u16* __restrict__ Qb, u16* __restrict__ Kb,
        u16* __restrict__ Vb) {
    __shared__ alignas(16) u16 As[BM * BK];
    __shared__ alignas(16) u16 Bs[BN * BK];
    const int id = blockIdx.x + 64 * blockIdx.y;   // 0..1535
    const int xcd = id & 7;
    const int k = id >> 3;                          // 0..191
    const int xv = xcd * 8 + (k & 7);               // m-panel: 8 per XCD
    const int yv = k >> 3;                          // 0..23 (mat, n-panel)
    const int m0 = xv * BM;
    const int mat = yv >> 3;
    const int n0 = (yv & 7) * BN;
    const u16* Wb = W3 + (size_t)mat * DM * DM;
    const int tid = threadIdx.x;
    const int w = tid >> 6;
    const int lane = tid & 63;
    const int quad = lane >> 4, l16 = lane & 15;
    const int wr = (w >> 1) * 64;
    const int wc = (w & 1) * 64;

    const int c0 = w * 2;
    const int srow = c0 * 16 + (lane >> 2);
    const int scol = (lane & 3) * 8;
    const u16* ag = A  + (size_t)(m0 + srow) * DM + scol;
    const u16* bg = Wb + (size_t)(n0 + srow) * DM + scol;
    u16* as0 = As + c0 * 512;
    u16* bs0 = Bs + c0 * 512;

    f32x4 acc[4][4];
#pragma unroll
    for (int i = 0; i < 4; i++)
#pragma unroll
        for (int j = 0; j < 4; j++) acc[i][j] = (f32x4){0.f, 0.f, 0.f, 0.f};

    for (int k0 = 0; k0 < DM; k0 += BK) {
        __builtin_amdgcn_global_load_lds((g_void*)(ag + k0),            (lds_void*)as0,         16, 0, 0);
        __builtin_amdgcn_global_load_lds((g_void*)(ag + k0 + 16 * DM),  (lds_void*)(as0 + 512), 16, 0, 0);
        __builtin_amdgcn_global_load_lds((g_void*)(bg + k0),            (lds_void*)bs0,         16, 0, 0);
        __builtin_amdgcn_global_load_lds((g_void*)(bg + k0 + 16 * DM),  (lds_void*)(bs0 + 512), 16, 0, 0);
        __syncthreads();
        bf16x8 af[4], bfr[4];
#pragma unroll
        for (int mt = 0; mt < 4; mt++)
            af[mt] = *(const bf16x8*)(As + (wr + mt * 16 + l16) * BK + quad * 8);
#pragma unroll
        for (int nt = 0; nt < 4; nt++)
            bfr[nt] = *(const bf16x8*)(Bs + (wc + nt * 16 + l16) * BK + quad * 8);
#pragma unroll
        for (int mt = 0; mt < 4; mt++)
#pragma unroll
            for (int nt = 0; nt < 4; nt++)
                acc[mt][nt] = __builtin_amdgcn_mfma_f32_16x16x32_bf16(af[mt], bfr[nt], acc[mt][nt], 0, 0, 0);
        __syncthreads();
    }

    u16* outb = mat == 0 ? Qb : (mat == 1 ? Kb : Vb);
#pragma unroll
    for (int mt = 0; mt < 4; mt++) {
#pragma unroll
        for (int nt = 0; nt < 4; nt++) {
#pragma unroll
            for (int r = 0; r < 4; r++) {
                const int row = m0 + wr + mt * 16 + quad * 4 + r;
                const int col = n0 + wc + nt * 16 + l16;
                const float val = acc[mt][nt][r];
                const int b = row >> 11, t = row & (TSEQ - 1);
                const int h = col >> 6, d = col & (DH - 1);
                if (mat == 2)
                    outb[((size_t)(b * NH + h) * DH + d) * TSEQ + t] = f2b(val);
                else
                    outb[((size_t)(b * NH + h) * TSEQ + t) * DH + d] = f2b(val);
            }
        }
    }
}

// Output projection + residual: out = y @ Wo^T + x0 (fp32 out).
// Same XCD-locality remap (A-panels resident per XCD, W streamed).
__global__ __launch_bounds__(256) void gemm_wo(const u16* __restrict__ A,
        const u16* __restrict__ Wb, const float* __restrict__ X0,
        float* __restrict__ out) {
    __shared__ alignas(16) u16 As[BM * BK];
    __shared__ alignas(16) u16 Bs[BN * BK];
    const int id = blockIdx.x + 64 * blockIdx.y;   // 0..511
    const int xcd = id & 7;
    const int k = id >> 3;                          // 0..63
    const int m0 = (xcd * 8 + (k & 7)) * BM;
    const int n0 = (k >> 3) * BN;
    const int tid = threadIdx.x;
    const int w = tid >> 6;
    const int lane = tid & 63;
    const int quad = lane >> 4, l16 = lane & 15;
    const int wr = (w >> 1) * 64;
    const int wc = (w & 1) * 64;

    const int c0 = w * 2;
    const int srow = c0 * 16 + (lane >> 2);
    const int scol = (lane & 3) * 8;
    const u16* ag = A  + (size_t)(m0 + srow) * DM + scol;
    const u16* bg = Wb + (size_t)(n0 + srow) * DM + scol;
    u16* as0 = As + c0 * 512;
    u16* bs0 = Bs + c0 * 512;

    f32x4 acc[4][4];
#pragma unroll
    for (int i = 0; i < 4; i++)
#pragma unroll
        for (int j = 0; j < 4; j++) acc[i][j] = (f32x4){0.f, 0.f, 0.f, 0.f};

    for (int k0 = 0; k0 < DM; k0 += BK) {
        __builtin_amdgcn_global_load_lds((g_void*)(ag + k0),            (lds_void*)as0,         16, 0, 0);
        __builtin_amdgcn_global_load_lds((g_void*)(ag + k0 + 16 * DM),  (lds_void*)(as0 + 512), 16, 0, 0);
        __builtin_amdgcn_global_load_lds((g_void*)(bg + k0),            (lds_void*)bs0,         16, 0, 0);
        __builtin_amdgcn_global_load_lds((g_void*)(bg + k0 + 16 * DM),  (lds_void*)(bs0 + 512), 16, 0, 0);
        __syncthreads();
        bf16x8 af[4], bfr[4];
#pragma unroll
        for (int mt = 0; mt < 4; mt++)
            af[mt] = *(const bf16x8*)(As + (wr + mt * 16 + l16) * BK + quad * 8);
#pragma unroll
        for (int nt = 0; nt < 4; nt++)
            bfr[nt] = *(const bf16x8*)(Bs + (wc + nt * 16 + l16) * BK + quad * 8);
#pragma unroll
        for (int mt = 0; mt < 4; mt++)
#pragma unroll
            for (int nt = 0; nt < 4; nt++)
                acc[mt][nt] = __builtin_amdgcn_mfma_f32_16x16x32_bf16(af[mt], bfr[nt], acc[mt][nt], 0, 0, 0);
        __syncthreads();
    }

#pragma unroll
    for (int mt = 0; mt < 4; mt++) {
#pragma unroll
        for (int nt = 0; nt < 4; nt++) {
#pragma unroll
            for (int r = 0; r < 4; r++) {
                const int row = m0 + wr + mt * 16 + quad * 4 + r;
                const int col = n0 + wc + nt * 16 + l16;
                const size_t idx = (size_t)row * DM + col;
                out[idx] = acc[mt][nt][r] + X0[idx];
            }
        }
    }
}

// ---------------- Flash attention: in-register P, paired tiles, split-j ----------
// grid (16, B*H), 512 threads = 8 waves: rg = w&3 picks the 16-q-row group,
// jg = w>>2 picks the j-interleave (j0 = jg*32, stride 64). Paired tiles
// {p, 31-p} -> identical work per block.
//
// XCD-locality remap: flat id round-robins over XCDs, so assign each XCD 8
// consecutive bh (all 16 p-blocks of each). Per-XCD K+V working set =
// 8 x 512KB = 4MB ~= one XCD's L2. Round 3 showed the kernel pinned at the
// ~8 TB/s cross-XCD fabric (2.1 GB of KV re-reads missing L2): doubling
// occupancy moved nothing. This remap turns those misses into L2 hits.
//
// Swapped QK^T (S = mfma(K, Q)) with permuted K A-frag rows keeps P entirely
// in registers. Fixed max FM=8 makes softmax additive over j-slices: the two
// jg partials combine as o += o', oL += oL' (one LDS exchange per tile).
__global__ __launch_bounds__(512, 8) void attn_kernel(const u16* __restrict__ Q,
        const u16* __restrict__ K, const u16* __restrict__ Vt,
        const float* __restrict__ rel, u16* __restrict__ y) {
    const int id = blockIdx.x + 16 * blockIdx.y;    // 0..1023
    const int xcd = id & 7;
    const int idx = id >> 3;                        // 0..127
    const int bh = xcd * 8 + (idx & 7);             // 8 bh per XCD
    const int p = idx >> 3;                         // 0..15
    const int h = bh & (NH - 1);
    const int b = bh >> 4;
    const int tid = threadIdx.x;
    const int w = tid >> 6, lane = tid & 63;
    const int rg = w & 3, jg = w >> 2;
    const int quad = lane >> 4, l16 = lane & 15;

    __shared__ alignas(16) float rel_s[NREL];
    __shared__ alignas(16) f32x4 cb[4][5][64];      // 20 KB combine buffer
    if (tid < NREL) rel_s[tid] = rel[h * NREL + tid];
    __syncthreads();
    const float r128 = rel_s[128];

    const u16* Qh = Q + (size_t)bh * TSEQ * DH;
    const u16* Kh = K + (size_t)bh * TSEQ * DH;
    const u16* Vh = Vt + (size_t)bh * DH * TSEQ;

    bf16x8 ones;
#pragma unroll
    for (int j = 0; j < 8; j++) ones[j] = (short)0x3F80;

    // K A-frag row permutation base for this lane (g0 mapping, dh = quad*8)
    const int krow = (l16 & 3) + ((l16 >> 2) << 3); // 0..27
    const u16* kbase = Kh + (size_t)krow * DH + quad * 8;

    for (int ti = 0; ti < 2; ti++) {
        const int qt = ti ? (31 - p) : p;
        const int wq = qt * 64 + rg * 16;           // wave group's first q row
        const int gq = wq + l16;                    // this lane's q row
        const bf16x8 qf0 = *(const bf16x8*)(Qh + (size_t)gq * DH + quad * 8);
        const bf16x8 qf1 = *(const bf16x8*)(Qh + (size_t)gq * DH + 32 + quad * 8);

        f32x4 o[4];
#pragma unroll
        for (int i = 0; i < 4; i++) o[i] = (f32x4){0.f, 0.f, 0.f, 0.f};
        f32x4 oL = (f32x4){0.f, 0.f, 0.f, 0.f};
        const int jend = wq + 16;                   // wave-local causal bound

        for (int j0 = jg * 32; j0 < jend; j0 += 64) {
            const u16* kp = kbase + (size_t)j0 * DH;
            const bf16x8 k00 = *(const bf16x8*)(kp);
            const bf16x8 k01 = *(const bf16x8*)(kp + 32);
            const bf16x8 k10 = *(const bf16x8*)(kp + 4 * DH);
            const bf16x8 k11 = *(const bf16x8*)(kp + 4 * DH + 32);
            f32x4 s0 = (f32x4){0.f, 0.f, 0.f, 0.f};
            f32x4 s1 = (f32x4){0.f, 0.f, 0.f, 0.f};
            s0 = __builtin_amdgcn_mfma_f32_16x16x32_bf16(k00, qf0, s0, 0, 0, 0);
            s0 = __builtin_amdgcn_mfma_f32_16x16x32_bf16(k01, qf1, s0, 0, 0, 0);
            s1 = __builtin_amdgcn_mfma_f32_16x16x32_bf16(k10, qf0, s1, 0, 0, 0);
            s1 = __builtin_amdgcn_mfma_f32_16x16x32_bf16(k11, qf1, s1, 0, 0, 0);
            // lane holds S[j][q=gq]; s0[r]: j = j0+8*quad+r; s1[r]: j += 4

            float p0[4], p1[4];
            const int dq = gq - j0 - 8 * quad;      // dist for s0[r] is dq - r
            if (j0 + 159 < wq) {
                // fast path: every dist in tile > 128 -> bias = rel[128], no mask
#pragma unroll
                for (int r = 0; r < 4; r++) {
                    p0[r] = __expf(s0[r] + (r128 - FIXMAX));
                    p1[r] = __expf(s1[r] + (r128 - FIXMAX));
                }
            } else {
#pragma unroll
                for (int r = 0; r < 4; r++) {
                    const int d0 = dq - r;
                    const int d1 = dq - 4 - r;
                    const int c0 = d0 < 0 ? 0 : (d0 > 128 ? 128 : d0);
                    const int c1 = d1 < 0 ? 0 : (d1 > 128 ? 128 : d1);
                    float sv0 = s0[r] + rel_s[c0];
                    float sv1 = s1[r] + rel_s[c1];
                    sv0 = d0 >= 0 ? sv0 : NEGBIG;
                    sv1 = d1 >= 0 ? sv1 : NEGBIG;
                    p0[r] = __expf(sv0 - FIXMAX);   // masked -> exp(-huge) = 0
                    p1[r] = __expf(sv1 - FIXMAX);
                }
            }
            bf16x8 pf;                              // A-frag: k = quad*8 + e
            pf[0] = (short)f2b(p0[0]); pf[1] = (short)f2b(p0[1]);
            pf[2] = (short)f2b(p0[2]); pf[3] = (short)f2b(p0[3]);
            pf[4] = (short)f2b(p1[0]); pf[5] = (short)f2b(p1[1]);
            pf[6] = (short)f2b(p1[2]); pf[7] = (short)f2b(p1[3]);

            bf16x8 vf[4];
#pragma unroll
            for (int dt = 0; dt < 4; dt++)
                vf[dt] = *(const bf16x8*)(Vh + (size_t)(dt * 16 + l16) * TSEQ + j0 + quad * 8);
#pragma unroll
            for (int dt = 0; dt < 4; dt++)
                o[dt] = __builtin_amdgcn_mfma_f32_16x16x32_bf16(pf, vf[dt], o[dt], 0, 0, 0);
            oL = __builtin_amdgcn_mfma_f32_16x16x32_bf16(pf, ones, oL, 0, 0, 0);
        }

        if (jg == 1) {
#pragma unroll
            for (int dt = 0; dt < 4; dt++) cb[rg][dt][lane] = o[dt];
            cb[rg][4][lane] = oL;
        }
        __syncthreads();
        if (jg == 0) {
#pragma unroll
            for (int dt = 0; dt < 4; dt++) {
                const f32x4 op = cb[rg][dt][lane];
                o[dt].x += op.x; o[dt].y += op.y; o[dt].z += op.z; o[dt].w += op.w;
            }
            const f32x4 oLp = cb[rg][4][lane];
            oL.x += oLp.x; oL.y += oLp.y; oL.z += oLp.z; oL.w += oLp.w;
#pragma unroll
            for (int dt = 0; dt < 4; dt++) {
#pragma unroll
                for (int r = 0; r < 4; r++) {
                    const float val = o[dt][r] / oL[r];
                    const int t = wq + quad * 4 + r;
                    y[((size_t)(b * TSEQ + t)) * DM + h * DH + dt * 16 + l16] = f2b(val);
                }
            }
        }
        __syncthreads();   // cb reused by next ti
    }
}

extern "C" void kernel_launch(void* const* d_in, const int* in_sizes, int n_in,
                              void* d_out, int out_size, void* d_ws, size_t ws_size,
                              hipStream_t stream) {
    const float* x   = (const float*)d_in[0];
    const float* Wq  = (const float*)d_in[1];
    const float* Wk  = (const float*)d_in[2];
    const float* Wv  = (const float*)d_in[3];
    const float* Wo  = (const float*)d_in[4];
    const float* rel = (const float*)d_in[5];
    const float* gam = (const float*)d_in[6];
    const float* bet = (const float*)d_in[7];
    u16* ws = (u16*)d_ws;
    const size_t SZ = (size_t)BATCH * TSEQ * DM;
    const size_t need_bytes = 4 * SZ * sizeof(u16);

    if (n_in != 8) {
        fill_kernel<<<4096, 256, 0, stream>>>((float*)d_out, out_size, 8000.0f);
        return;
    }
    if (ws_size < need_bytes) {
        fill_kernel<<<4096, 256, 0, stream>>>((float*)d_out, out_size, 9500.0f);
        return;
    }

    u16* xn = ws;             // [B*T, D] normalized input (bf16)
    u16* Qb = ws + SZ;        // bf16 [b][h][t][d], pre-scaled by 1/8 (folded into Wq)
    u16* Kb = ws + 2 * SZ;    // bf16 [b][h][t][d]
    u16* Vb = ws + 3 * SZ;    // bf16 [b][h][d][t]  (transposed for PV B-frags)
    u16* y  = xn;             // attention output reuses xn region

    // bf16 weight scratch lives in d_out (33.5 MB; only written by the final
    // GEMM): [0,2MB) Wq*0.125, [2,4MB) Wk, [4,6MB) Wv. Wo-bf16 goes into Qb
    // after attn frees it.
    u16* wscr = (u16*)d_out;
    const int W4 = (DM * DM) / 4;   // 2^18 vec4 per matrix

    ln_kernel<<<BATCH * TSEQ, 256, 0, stream>>>(x, gam, bet, xn);
    cvt3_kernel<<<3 * W4 / 256, 256, 0, stream>>>(Wq, Wk, Wv, wscr);
    gemm_qkv<<<dim3(BATCH * TSEQ / BM, 24), 256, 0, stream>>>(xn, wscr, Qb, Kb, Vb);
    attn_kernel<<<dim3(16, BATCH * NH), 512, 0, stream>>>(Qb, Kb, Vb, rel, y);
    cvt1_kernel<<<W4 / 256, 256, 0, stream>>>(Wo, Qb, W4);   // Qb free after attn
    gemm_wo<<<dim3(BATCH * TSEQ / BM, DM / BN), 256, 0, stream>>>(y, Qb, x, (float*)d_out);
}

// Round 5
// 295.637 us; speedup vs baseline: 1.5414x; 1.5414x over previous
//
#include <hip/hip_runtime.h>
#include <math.h>

#define TSEQ 2048
#define BATCH 4
#define NH 16
#define DH 64
#define DM 1024
#define NREL 129
#define NEGBIG (-1.0e30f)
#define FIXMAX 8.0f

typedef unsigned short u16;
typedef unsigned int u32;
typedef __attribute__((ext_vector_type(8))) short bf16x8;
typedef __attribute__((ext_vector_type(4))) float f32x4;
typedef __attribute__((ext_vector_type(4))) unsigned short u16x4;

typedef __attribute__((address_space(3))) void lds_void;
typedef const __attribute__((address_space(1))) void g_void;

__device__ inline u16 f2b(float f) {
    union { float f; u32 i; } c; c.f = f;
    u32 x = c.i;
    return (u16)((x + 0x7fffu + ((x >> 16) & 1u)) >> 16);
}

__global__ __launch_bounds__(256) void fill_kernel(float* __restrict__ out, int n, float v) {
    for (int i = blockIdx.x * 256 + threadIdx.x; i < n; i += gridDim.x * 256)
        out[i] = v;
}

// ---------------- LayerNorm: fp32 in -> bf16 out, one block per row ----------------
__global__ __launch_bounds__(256) void ln_kernel(const float* __restrict__ x,
        const float* __restrict__ gamma, const float* __restrict__ beta,
        u16* __restrict__ xn) {
    const int row = blockIdx.x;
    const int tid = threadIdx.x;
    const float* xr = x + (size_t)row * DM;
    f32x4 xv = *(const f32x4*)(xr + tid * 4);
    float s = xv.x + xv.y + xv.z + xv.w;
    float s2 = xv.x*xv.x + xv.y*xv.y + xv.z*xv.z + xv.w*xv.w;
#pragma unroll
    for (int off = 32; off > 0; off >>= 1) {
        s  += __shfl_down(s, off, 64);
        s2 += __shfl_down(s2, off, 64);
    }
    __shared__ alignas(16) float red[8];
    const int wv = tid >> 6, ln = tid & 63;
    if (ln == 0) { red[wv] = s; red[4 + wv] = s2; }
    __syncthreads();
    s  = red[0] + red[1] + red[2] + red[3];
    s2 = red[4] + red[5] + red[6] + red[7];
    const float mu = s * (1.0f / DM);
    float var = s2 * (1.0f / DM) - mu * mu;
    var = var > 0.0f ? var : 0.0f;
    const float rstd = rsqrtf(var + 1e-5f);
    f32x4 gv = *(const f32x4*)(gamma + tid * 4);
    f32x4 bv = *(const f32x4*)(beta + tid * 4);
    u16x4 ov;
    ov.x = f2b((xv.x - mu) * rstd * gv.x + bv.x);
    ov.y = f2b((xv.y - mu) * rstd * gv.y + bv.y);
    ov.z = f2b((xv.z - mu) * rstd * gv.z + bv.z);
    ov.w = f2b((xv.w - mu) * rstd * gv.w + bv.w);
    *(u16x4*)(xn + (size_t)row * DM + tid * 4) = ov;
}

// ---------------- Weight conversion: fp32 -> bf16, done ONCE ----------------
__global__ __launch_bounds__(256) void cvt3_kernel(const float* __restrict__ a,
        const float* __restrict__ b, const float* __restrict__ c,
        u16* __restrict__ dst) {
    const int i = blockIdx.x * 256 + threadIdx.x;      // vec4 index, [0, 3*2^18)
    const int m = i >> 18;                              // 2^18 vec4 per 1024x1024
    const int j = i & 0x3FFFF;
    const float* src = m == 0 ? a : (m == 1 ? b : c);
    const float scale = m == 0 ? 0.125f : 1.0f;
    f32x4 v = *(const f32x4*)(src + (size_t)j * 4);
    u16x4 o;
    o.x = f2b(v.x * scale); o.y = f2b(v.y * scale);
    o.z = f2b(v.z * scale); o.w = f2b(v.w * scale);
    *(u16x4*)(dst + (size_t)i * 4) = o;
}

__global__ __launch_bounds__(256) void cvt1_kernel(const float* __restrict__ src,
        u16* __restrict__ dst, int n4) {
    const int i = blockIdx.x * 256 + threadIdx.x;
    if (i >= n4) return;
    f32x4 v = *(const f32x4*)(src + (size_t)i * 4);
    u16x4 o;
    o.x = f2b(v.x); o.y = f2b(v.y); o.z = f2b(v.z); o.w = f2b(v.w);
    *(u16x4*)(dst + (size_t)i * 4) = o;
}

// ---------------- GEMM (m97 structure): 128x128 tile, BK=32 ----------------
#define BM 128
#define BN 128
#define BK 32

// Fragment-major layouts for attention operands (pure permutations of Q/K/V):
// every attn inner-loop global load becomes base + lane*16B (fully coalesced
// 1KB wave loads) instead of a 16-segment gather. Round-4 evidence: attn time
// was invariant to occupancy AND data residency -> TA/TCP request-rate bound
// on the scattered fragment gathers (128 x 64B segments per wave-iter).
//
// Qf: per bh, per 16-q block: 2 chunks (d 0-31, 32-63) of 512 u16;
//     element (t,d) -> chunk (d>>5), slot lane=( (d>>3)&3 )*16 + (t&15), e=d&7.
// Kf: per bh, per 32-j block: 4 chunks {k00,k01,k10,k11}:
//     jr=j&31: hi=(jr>>2)&1, l16=(jr&3)|((jr>>3)<<2); chunk = hi*2 + (d>>5);
//     slot lane = ((d>>3)&3)*16 + l16, e = d&7.
// Vf: per bh, per 32-j block: 4 chunks dt=d>>4:
//     slot lane = ((t>>3)&3)*16 + (d&15), e = t&7.
__global__ __launch_bounds__(256) void gemm_qkv(const u16* __restrict__ A,
        const u16* __restrict__ W3, u16* __restrict__ Qb, u16* __restrict__ Kb,
        u16* __restrict__ Vb) {
    __shared__ alignas(16) u16 As[BM * BK];
    __shared__ alignas(16) u16 Bs[BN * BK];
    const int id = blockIdx.x + 64 * blockIdx.y;   // 0..1535
    const int xcd = id & 7;
    const int k = id >> 3;                          // 0..191
    const int xv = xcd * 8 + (k & 7);               // m-panel: 8 per XCD
    const int yv = k >> 3;                          // 0..23 (mat, n-panel)
    const int m0 = xv * BM;
    const int mat = yv >> 3;
    const int n0 = (yv & 7) * BN;
    const u16* Wb = W3 + (size_t)mat * DM * DM;
    const int tid = threadIdx.x;
    const int w = tid >> 6;
    const int lane = tid & 63;
    const int quad = lane >> 4, l16 = lane & 15;
    const int wr = (w >> 1) * 64;
    const int wc = (w & 1) * 64;

    const int c0 = w * 2;
    const int srow = c0 * 16 + (lane >> 2);
    const int scol = (lane & 3) * 8;
    const u16* ag = A  + (size_t)(m0 + srow) * DM + scol;
    const u16* bg = Wb + (size_t)(n0 + srow) * DM + scol;
    u16* as0 = As + c0 * 512;
    u16* bs0 = Bs + c0 * 512;

    f32x4 acc[4][4];
#pragma unroll
    for (int i = 0; i < 4; i++)
#pragma unroll
        for (int j = 0; j < 4; j++) acc[i][j] = (f32x4){0.f, 0.f, 0.f, 0.f};

    for (int k0 = 0; k0 < DM; k0 += BK) {
        __builtin_amdgcn_global_load_lds((g_void*)(ag + k0),            (lds_void*)as0,         16, 0, 0);
        __builtin_amdgcn_global_load_lds((g_void*)(ag + k0 + 16 * DM),  (lds_void*)(as0 + 512), 16, 0, 0);
        __builtin_amdgcn_global_load_lds((g_void*)(bg + k0),            (lds_void*)bs0,         16, 0, 0);
        __builtin_amdgcn_global_load_lds((g_void*)(bg + k0 + 16 * DM),  (lds_void*)(bs0 + 512), 16, 0, 0);
        __syncthreads();
        bf16x8 af[4], bfr[4];
#pragma unroll
        for (int mt = 0; mt < 4; mt++)
            af[mt] = *(const bf16x8*)(As + (wr + mt * 16 + l16) * BK + quad * 8);
#pragma unroll
        for (int nt = 0; nt < 4; nt++)
            bfr[nt] = *(const bf16x8*)(Bs + (wc + nt * 16 + l16) * BK + quad * 8);
#pragma unroll
        for (int mt = 0; mt < 4; mt++)
#pragma unroll
            for (int nt = 0; nt < 4; nt++)
                acc[mt][nt] = __builtin_amdgcn_mfma_f32_16x16x32_bf16(af[mt], bfr[nt], acc[mt][nt], 0, 0, 0);
        __syncthreads();
    }

    u16* outb = mat == 0 ? Qb : (mat == 1 ? Kb : Vb);
#pragma unroll
    for (int mt = 0; mt < 4; mt++) {
#pragma unroll
        for (int nt = 0; nt < 4; nt++) {
#pragma unroll
            for (int r = 0; r < 4; r++) {
                const int row = m0 + wr + mt * 16 + quad * 4 + r;
                const int col = n0 + wc + nt * 16 + l16;
                const float val = acc[mt][nt][r];
                const int b = row >> 11, t = row & (TSEQ - 1);
                const int h = col >> 6, d = col & (DH - 1);
                const size_t bh = (size_t)(b * NH + h);
                size_t addr;
                if (mat == 0) {
                    addr = ((bh * 128 + (t >> 4)) * 2 + (d >> 5)) * 512
                         + ((((d >> 3) & 3) << 4) + (t & 15)) * 8 + (d & 7);
                } else if (mat == 1) {
                    const int jr = t & 31;
                    const int hi = (jr >> 2) & 1;
                    const int lk = (jr & 3) | ((jr >> 3) << 2);
                    addr = ((bh * 64 + (t >> 5)) * 4 + hi * 2 + (d >> 5)) * 512
                         + ((((d >> 3) & 3) << 4) + lk) * 8 + (d & 7);
                } else {
                    addr = ((bh * 64 + (t >> 5)) * 4 + (d >> 4)) * 512
                         + ((((t >> 3) & 3) << 4) + (d & 15)) * 8 + (t & 7);
                }
                outb[addr] = f2b(val);
            }
        }
    }
}

// Output projection + residual: out = y @ Wo^T + x0 (fp32 out).
// Same XCD-locality remap (A-panels resident per XCD, W streamed).
__global__ __launch_bounds__(256) void gemm_wo(const u16* __restrict__ A,
        const u16* __restrict__ Wb, const float* __restrict__ X0,
        float* __restrict__ out) {
    __shared__ alignas(16) u16 As[BM * BK];
    __shared__ alignas(16) u16 Bs[BN * BK];
    const int id = blockIdx.x + 64 * blockIdx.y;   // 0..511
    const int xcd = id & 7;
    const int k = id >> 3;                          // 0..63
    const int m0 = (xcd * 8 + (k & 7)) * BM;
    const int n0 = (k >> 3) * BN;
    const int tid = threadIdx.x;
    const int w = tid >> 6;
    const int lane = tid & 63;
    const int quad = lane >> 4, l16 = lane & 15;
    const int wr = (w >> 1) * 64;
    const int wc = (w & 1) * 64;

    const int c0 = w * 2;
    const int srow = c0 * 16 + (lane >> 2);
    const int scol = (lane & 3) * 8;
    const u16* ag = A  + (size_t)(m0 + srow) * DM + scol;
    const u16* bg = Wb + (size_t)(n0 + srow) * DM + scol;
    u16* as0 = As + c0 * 512;
    u16* bs0 = Bs + c0 * 512;

    f32x4 acc[4][4];
#pragma unroll
    for (int i = 0; i < 4; i++)
#pragma unroll
        for (int j = 0; j < 4; j++) acc[i][j] = (f32x4){0.f, 0.f, 0.f, 0.f};

    for (int k0 = 0; k0 < DM; k0 += BK) {
        __builtin_amdgcn_global_load_lds((g_void*)(ag + k0),            (lds_void*)as0,         16, 0, 0);
        __builtin_amdgcn_global_load_lds((g_void*)(ag + k0 + 16 * DM),  (lds_void*)(as0 + 512), 16, 0, 0);
        __builtin_amdgcn_global_load_lds((g_void*)(bg + k0),            (lds_void*)bs0,         16, 0, 0);
        __builtin_amdgcn_global_load_lds((g_void*)(bg + k0 + 16 * DM),  (lds_void*)(bs0 + 512), 16, 0, 0);
        __syncthreads();
        bf16x8 af[4], bfr[4];
#pragma unroll
        for (int mt = 0; mt < 4; mt++)
            af[mt] = *(const bf16x8*)(As + (wr + mt * 16 + l16) * BK + quad * 8);
#pragma unroll
        for (int nt = 0; nt < 4; nt++)
            bfr[nt] = *(const bf16x8*)(Bs + (wc + nt * 16 + l16) * BK + quad * 8);
#pragma unroll
        for (int mt = 0; mt < 4; mt++)
#pragma unroll
            for (int nt = 0; nt < 4; nt++)
                acc[mt][nt] = __builtin_amdgcn_mfma_f32_16x16x32_bf16(af[mt], bfr[nt], acc[mt][nt], 0, 0, 0);
        __syncthreads();
    }

#pragma unroll
    for (int mt = 0; mt < 4; mt++) {
#pragma unroll
        for (int nt = 0; nt < 4; nt++) {
#pragma unroll
            for (int r = 0; r < 4; r++) {
                const int row = m0 + wr + mt * 16 + quad * 4 + r;
                const int col = n0 + wc + nt * 16 + l16;
                const size_t idx = (size_t)row * DM + col;
                out[idx] = acc[mt][nt][r] + X0[idx];
            }
        }
    }
}

// ---------------- Flash attention: frag-major operands, in-register P ------------
// grid (16, B*H), 512 threads = 8 waves: rg = w&3 picks the 16-q-row group,
// jg = w>>2 picks the j-interleave (j0 = jg*32, stride 64). Paired tiles
// {p, 31-p} -> identical work per block. XCD remap: 8 bh per XCD (L2-resident KV).
//
// All Q/K/V loads are now base + lane*16B from the frag-major layouts written
// by gemm_qkv: 1KB fully-coalesced wave loads (was: 16-segment gathers that
// saturated the TA/TCP request path -> rounds 1-4 pinned at ~250us regardless
// of occupancy or data residency).
//
// Swapped QK^T (S = mfma(K, Q)) keeps P entirely in registers. Fixed max FM=8
// makes softmax additive over j-slices: jg partials combine as o += o',
// oL += oL' (one LDS exchange per tile, no rescale).
__global__ __launch_bounds__(512, 8) void attn_kernel(const u16* __restrict__ Q,
        const u16* __restrict__ K, const u16* __restrict__ Vt,
        const float* __restrict__ rel, u16* __restrict__ y) {
    const int id = blockIdx.x + 16 * blockIdx.y;    // 0..1023
    const int xcd = id & 7;
    const int idx = id >> 3;                        // 0..127
    const int bh = xcd * 8 + (idx & 7);             // 8 bh per XCD
    const int p = idx >> 3;                         // 0..15
    const int h = bh & (NH - 1);
    const int b = bh >> 4;
    const int tid = threadIdx.x;
    const int w = tid >> 6, lane = tid & 63;
    const int rg = w & 3, jg = w >> 2;
    const int quad = lane >> 4, l16 = lane & 15;

    __shared__ alignas(16) float rel_s[NREL];
    __shared__ alignas(16) f32x4 cb[4][5][64];      // 20 KB combine buffer
    if (tid < NREL) rel_s[tid] = rel[h * NREL + tid];
    __syncthreads();
    const float r128 = rel_s[128];

    const u16* Qh = Q  + (size_t)bh * TSEQ * DH;    // frag-major regions
    const u16* Kh = K  + (size_t)bh * TSEQ * DH;
    const u16* Vh = Vt + (size_t)bh * TSEQ * DH;

    bf16x8 ones;
#pragma unroll
    for (int j = 0; j < 8; j++) ones[j] = (short)0x3F80;

    for (int ti = 0; ti < 2; ti++) {
        const int qt = ti ? (31 - p) : p;
        const int wq = qt * 64 + rg * 16;           // wave group's first q row
        const int gq = wq + l16;                    // this lane's q row
        const u16* qb = Qh + (size_t)(wq >> 4) * 1024 + lane * 8;
        const bf16x8 qf0 = *(const bf16x8*)(qb);
        const bf16x8 qf1 = *(const bf16x8*)(qb + 512);

        f32x4 o[4];
#pragma unroll
        for (int i = 0; i < 4; i++) o[i] = (f32x4){0.f, 0.f, 0.f, 0.f};
        f32x4 oL = (f32x4){0.f, 0.f, 0.f, 0.f};
        const int jend = wq + 16;                   // wave-local causal bound

        for (int j0 = jg * 32; j0 < jend; j0 += 64) {
            const u16* kb = Kh + (size_t)(j0 >> 5) * 2048 + lane * 8;
            const bf16x8 k00 = *(const bf16x8*)(kb);
            const bf16x8 k01 = *(const bf16x8*)(kb + 512);
            const bf16x8 k10 = *(const bf16x8*)(kb + 1024);
            const bf16x8 k11 = *(const bf16x8*)(kb + 1536);
            f32x4 s0 = (f32x4){0.f, 0.f, 0.f, 0.f};
            f32x4 s1 = (f32x4){0.f, 0.f, 0.f, 0.f};
            s0 = __builtin_amdgcn_mfma_f32_16x16x32_bf16(k00, qf0, s0, 0, 0, 0);
            s0 = __builtin_amdgcn_mfma_f32_16x16x32_bf16(k01, qf1, s0, 0, 0, 0);
            s1 = __builtin_amdgcn_mfma_f32_16x16x32_bf16(k10, qf0, s1, 0, 0, 0);
            s1 = __builtin_amdgcn_mfma_f32_16x16x32_bf16(k11, qf1, s1, 0, 0, 0);
            // lane holds S[j][q=gq]; s0[r]: j = j0+8*quad+r; s1[r]: j += 4

            float p0[4], p1[4];
            const int dq = gq - j0 - 8 * quad;      // dist for s0[r] is dq - r
            if (j0 + 159 < wq) {
                // fast path: every dist in tile > 128 -> bias = rel[128], no mask
#pragma unroll
                for (int r = 0; r < 4; r++) {
                    p0[r] = __expf(s0[r] + (r128 - FIXMAX));
                    p1[r] = __expf(s1[r] + (r128 - FIXMAX));
                }
            } else {
#pragma unroll
                for (int r = 0; r < 4; r++) {
                    const int d0 = dq - r;
                    const int d1 = dq - 4 - r;
                    const int c0 = d0 < 0 ? 0 : (d0 > 128 ? 128 : d0);
                    const int c1 = d1 < 0 ? 0 : (d1 > 128 ? 128 : d1);
                    float sv0 = s0[r] + rel_s[c0];
                    float sv1 = s1[r] + rel_s[c1];
                    sv0 = d0 >= 0 ? sv0 : NEGBIG;
                    sv1 = d1 >= 0 ? sv1 : NEGBIG;
                    p0[r] = __expf(sv0 - FIXMAX);   // masked -> exp(-huge) = 0
                    p1[r] = __expf(sv1 - FIXMAX);
                }
            }
            bf16x8 pf;                              // A-frag: k = quad*8 + e
            pf[0] = (short)f2b(p0[0]); pf[1] = (short)f2b(p0[1]);
            pf[2] = (short)f2b(p0[2]); pf[3] = (short)f2b(p0[3]);
            pf[4] = (short)f2b(p1[0]); pf[5] = (short)f2b(p1[1]);
            pf[6] = (short)f2b(p1[2]); pf[7] = (short)f2b(p1[3]);

            const u16* vb = Vh + (size_t)(j0 >> 5) * 2048 + lane * 8;
            bf16x8 vf[4];
#pragma unroll
            for (int dt = 0; dt < 4; dt++)
                vf[dt] = *(const bf16x8*)(vb + dt * 512);
#pragma unroll
            for (int dt = 0; dt < 4; dt++)
                o[dt] = __builtin_amdgcn_mfma_f32_16x16x32_bf16(pf, vf[dt], o[dt], 0, 0, 0);
            oL = __builtin_amdgcn_mfma_f32_16x16x32_bf16(pf, ones, oL, 0, 0, 0);
        }

        if (jg == 1) {
#pragma unroll
            for (int dt = 0; dt < 4; dt++) cb[rg][dt][lane] = o[dt];
            cb[rg][4][lane] = oL;
        }
        __syncthreads();
        if (jg == 0) {
#pragma unroll
            for (int dt = 0; dt < 4; dt++) {
                const f32x4 op = cb[rg][dt][lane];
                o[dt].x += op.x; o[dt].y += op.y; o[dt].z += op.z; o[dt].w += op.w;
            }
            const f32x4 oLp = cb[rg][4][lane];
            oL.x += oLp.x; oL.y += oLp.y; oL.z += oLp.z; oL.w += oLp.w;
#pragma unroll
            for (int dt = 0; dt < 4; dt++) {
#pragma unroll
                for (int r = 0; r < 4; r++) {
                    const float val = o[dt][r] / oL[r];
                    const int t = wq + quad * 4 + r;
                    y[((size_t)(b * TSEQ + t)) * DM + h * DH + dt * 16 + l16] = f2b(val);
                }
            }
        }
        __syncthreads();   // cb reused by next ti
    }
}

extern "C" void kernel_launch(void* const* d_in, const int* in_sizes, int n_in,
                              void* d_out, int out_size, void* d_ws, size_t ws_size,
                              hipStream_t stream) {
    const float* x   = (const float*)d_in[0];
    const float* Wq  = (const float*)d_in[1];
    const float* Wk  = (const float*)d_in[2];
    const float* Wv  = (const float*)d_in[3];
    const float* Wo  = (const float*)d_in[4];
    const float* rel = (const float*)d_in[5];
    const float* gam = (const float*)d_in[6];
    const float* bet = (const float*)d_in[7];
    u16* ws = (u16*)d_ws;
    const size_t SZ = (size_t)BATCH * TSEQ * DM;
    const size_t need_bytes = 4 * SZ * sizeof(u16);

    if (n_in != 8) {
        fill_kernel<<<4096, 256, 0, stream>>>((float*)d_out, out_size, 8000.0f);
        return;
    }
    if (ws_size < need_bytes) {
        fill_kernel<<<4096, 256, 0, stream>>>((float*)d_out, out_size, 9500.0f);
        return;
    }

    u16* xn = ws;             // [B*T, D] normalized input (bf16)
    u16* Qb = ws + SZ;        // bf16 frag-major Q (pre-scaled by 1/8 via Wq)
    u16* Kb = ws + 2 * SZ;    // bf16 frag-major K
    u16* Vb = ws + 3 * SZ;    // bf16 frag-major V
    u16* y  = xn;             // attention output reuses xn region

    // bf16 weight scratch lives in d_out (33.5 MB; only written by the final
    // GEMM): [0,2MB) Wq*0.125, [2,4MB) Wk, [4,6MB) Wv. Wo-bf16 goes into Qb
    // after attn frees it.
    u16* wscr = (u16*)d_out;
    const int W4 = (DM * DM) / 4;   // 2^18 vec4 per matrix

    ln_kernel<<<BATCH * TSEQ, 256, 0, stream>>>(x, gam, bet, xn);
    cvt3_kernel<<<3 * W4 / 256, 256, 0, stream>>>(Wq, Wk, Wv, wscr);
    gemm_qkv<<<dim3(BATCH * TSEQ / BM, 24), 256, 0, stream>>>(xn, wscr, Qb, Kb, Vb);
    attn_kernel<<<dim3(16, BATCH * NH), 512, 0, stream>>>(Qb, Kb, Vb, rel, y);
    cvt1_kernel<<<W4 / 256, 256, 0, stream>>>(Wo, Qb, W4);   // Qb free after attn
    gemm_wo<<<dim3(BATCH * TSEQ / BM, DM / BN), 256, 0, stream>>>(y, Qb, x, (float*)d_out);
}

// Round 6
// 290.471 us; speedup vs baseline: 1.5689x; 1.0178x over previous
//
#include <hip/hip_runtime.h>
#include <math.h>

#define TSEQ 2048
#define BATCH 4
#define NH 16
#define DH 64
#define DM 1024
#define NREL 129
#define NEGBIG (-1.0e30f)
#define FIXMAX 8.0f

typedef unsigned short u16;
typedef unsigned int u32;
typedef __attribute__((ext_vector_type(8))) short bf16x8;
typedef __attribute__((ext_vector_type(4))) float f32x4;
typedef __attribute__((ext_vector_type(4))) unsigned short u16x4;

typedef __attribute__((address_space(3))) void lds_void;
typedef const __attribute__((address_space(1))) void g_void;

__device__ inline u16 f2b(float f) {
    union { float f; u32 i; } c; c.f = f;
    u32 x = c.i;
    return (u16)((x + 0x7fffu + ((x >> 16) & 1u)) >> 16);
}

__global__ __launch_bounds__(256) void fill_kernel(float* __restrict__ out, int n, float v) {
    for (int i = blockIdx.x * 256 + threadIdx.x; i < n; i += gridDim.x * 256)
        out[i] = v;
}

// ---------------- LayerNorm: fp32 in -> bf16 out, one block per row ----------------
__global__ __launch_bounds__(256) void ln_kernel(const float* __restrict__ x,
        const float* __restrict__ gamma, const float* __restrict__ beta,
        u16* __restrict__ xn) {
    const int row = blockIdx.x;
    const int tid = threadIdx.x;
    const float* xr = x + (size_t)row * DM;
    f32x4 xv = *(const f32x4*)(xr + tid * 4);
    float s = xv.x + xv.y + xv.z + xv.w;
    float s2 = xv.x*xv.x + xv.y*xv.y + xv.z*xv.z + xv.w*xv.w;
#pragma unroll
    for (int off = 32; off > 0; off >>= 1) {
        s  += __shfl_down(s, off, 64);
        s2 += __shfl_down(s2, off, 64);
    }
    __shared__ alignas(16) float red[8];
    const int wv = tid >> 6, ln = tid & 63;
    if (ln == 0) { red[wv] = s; red[4 + wv] = s2; }
    __syncthreads();
    s  = red[0] + red[1] + red[2] + red[3];
    s2 = red[4] + red[5] + red[6] + red[7];
    const float mu = s * (1.0f / DM);
    float var = s2 * (1.0f / DM) - mu * mu;
    var = var > 0.0f ? var : 0.0f;
    const float rstd = rsqrtf(var + 1e-5f);
    f32x4 gv = *(const f32x4*)(gamma + tid * 4);
    f32x4 bv = *(const f32x4*)(beta + tid * 4);
    u16x4 ov;
    ov.x = f2b((xv.x - mu) * rstd * gv.x + bv.x);
    ov.y = f2b((xv.y - mu) * rstd * gv.y + bv.y);
    ov.z = f2b((xv.z - mu) * rstd * gv.z + bv.z);
    ov.w = f2b((xv.w - mu) * rstd * gv.w + bv.w);
    *(u16x4*)(xn + (size_t)row * DM + tid * 4) = ov;
}

// ---------------- Weight conversion: fp32 -> bf16, done ONCE ----------------
__global__ __launch_bounds__(256) void cvt3_kernel(const float* __restrict__ a,
        const float* __restrict__ b, const float* __restrict__ c,
        u16* __restrict__ dst) {
    const int i = blockIdx.x * 256 + threadIdx.x;      // vec4 index, [0, 3*2^18)
    const int m = i >> 18;                              // 2^18 vec4 per 1024x1024
    const int j = i & 0x3FFFF;
    const float* src = m == 0 ? a : (m == 1 ? b : c);
    const float scale = m == 0 ? 0.125f : 1.0f;
    f32x4 v = *(const f32x4*)(src + (size_t)j * 4);
    u16x4 o;
    o.x = f2b(v.x * scale); o.y = f2b(v.y * scale);
    o.z = f2b(v.z * scale); o.w = f2b(v.w * scale);
    *(u16x4*)(dst + (size_t)i * 4) = o;
}

__global__ __launch_bounds__(256) void cvt1_kernel(const float* __restrict__ src,
        u16* __restrict__ dst, int n4) {
    const int i = blockIdx.x * 256 + threadIdx.x;
    if (i >= n4) return;
    f32x4 v = *(const f32x4*)(src + (size_t)i * 4);
    u16x4 o;
    o.x = f2b(v.x); o.y = f2b(v.y); o.z = f2b(v.z); o.w = f2b(v.w);
    *(u16x4*)(dst + (size_t)i * 4) = o;
}

// ---------------- GEMM (m97 structure): 128x128 tile, BK=32 ----------------
#define BM 128
#define BN 128
#define BK 32

// Fragment-major layouts for attention operands (pure permutations of Q/K/V):
// every attn inner-loop global load becomes base + lane*16B (fully coalesced
// 1KB wave loads). Round-5 counters: the producer's direct frag-major SCATTER
// stores (64x 2B scattered stores/lane) made gemm_qkv itself TA-bound (89us,
// MfmaUtil 23%). Fix: stage the C quadrant through the (dead after K-loop)
// As/Bs LDS, then emit each 1KB chunk as ONE coalesced wave store.
//
// Qf: per bh, per 16-q block: 2 chunks (d 0-31, 32-63) of 512 u16;
//     (t,d) -> chunk (d>>5), slot = ((d>>3)&3)*16 + (t&15), e = d&7.
// Kf: per bh, per 32-j block: 4 chunks {k00,k01,k10,k11}:
//     jr=j&31: hi=(jr>>2)&1, lk=(jr&3)|((jr>>3)<<2); chunk = hi*2 + (d>>5);
//     slot = ((d>>3)&3)*16 + lk, e = d&7.
// Vf: per bh, per 32-j block: 4 chunks dt=d>>4:
//     slot = ((t>>3)&3)*16 + (d&15), e = t&7.
__global__ __launch_bounds__(256) void gemm_qkv(const u16* __restrict__ A,
        const u16* __restrict__ W3, u16* __restrict__ Qb, u16* __restrict__ Kb,
        u16* __restrict__ Vb) {
    __shared__ alignas(16) u16 sh[8192];            // As(8KB) + Bs(8KB); reused by epilogue
    u16* As = sh;
    u16* Bs = sh + 4096;
    const int id = blockIdx.x + 64 * blockIdx.y;   // 0..1535
    const int xcd = id & 7;
    const int k = id >> 3;                          // 0..191
    const int xv = xcd * 8 + (k & 7);               // m-panel: 8 per XCD
    const int yv = k >> 3;                          // 0..23 (mat, n-panel)
    const int m0 = xv * BM;
    const int mat = yv >> 3;
    const int n0 = (yv & 7) * BN;
    const u16* Wb = W3 + (size_t)mat * DM * DM;
    const int tid = threadIdx.x;
    const int w = tid >> 6;
    const int lane = tid & 63;
    const int quad = lane >> 4, l16 = lane & 15;
    const int wr = (w >> 1) * 64;
    const int wc = (w & 1) * 64;

    const int c0 = w * 2;
    const int srow = c0 * 16 + (lane >> 2);
    const int scol = (lane & 3) * 8;
    const u16* ag = A  + (size_t)(m0 + srow) * DM + scol;
    const u16* bg = Wb + (size_t)(n0 + srow) * DM + scol;
    u16* as0 = As + c0 * 512;
    u16* bs0 = Bs + c0 * 512;

    f32x4 acc[4][4];
#pragma unroll
    for (int i = 0; i < 4; i++)
#pragma unroll
        for (int j = 0; j < 4; j++) acc[i][j] = (f32x4){0.f, 0.f, 0.f, 0.f};

    for (int k0 = 0; k0 < DM; k0 += BK) {
        __builtin_amdgcn_global_load_lds((g_void*)(ag + k0),            (lds_void*)as0,         16, 0, 0);
        __builtin_amdgcn_global_load_lds((g_void*)(ag + k0 + 16 * DM),  (lds_void*)(as0 + 512), 16, 0, 0);
        __builtin_amdgcn_global_load_lds((g_void*)(bg + k0),            (lds_void*)bs0,         16, 0, 0);
        __builtin_amdgcn_global_load_lds((g_void*)(bg + k0 + 16 * DM),  (lds_void*)(bs0 + 512), 16, 0, 0);
        __syncthreads();
        bf16x8 af[4], bfr[4];
#pragma unroll
        for (int mt = 0; mt < 4; mt++)
            af[mt] = *(const bf16x8*)(As + (wr + mt * 16 + l16) * BK + quad * 8);
#pragma unroll
        for (int nt = 0; nt < 4; nt++)
            bfr[nt] = *(const bf16x8*)(Bs + (wc + nt * 16 + l16) * BK + quad * 8);
#pragma unroll
        for (int mt = 0; mt < 4; mt++)
#pragma unroll
            for (int nt = 0; nt < 4; nt++)
                acc[mt][nt] = __builtin_amdgcn_mfma_f32_16x16x32_bf16(af[mt], bfr[nt], acc[mt][nt], 0, 0, 0);
        __syncthreads();   // also guarantees As/Bs dead before epilogue reuses sh
    }

    // ---- Epilogue: per-wave 4KB LDS staging -> coalesced 1KB chunk stores ----
    // Wave quadrant = rows [tq, tq+64) x one head (h = (n0+wc)>>6), d in [0,64).
    // Index algebra (verified against the direct-scatter formulas):
    //   d = nt*16 + l16, nt = 2p+ntl  ->  d>>5 = p, (d>>3)&3 = ntl*2 + (l16>>3)
    //   t&15 = quad*4+r; K: hi = quad&1, lk = r + (quad>>1)*4 + (mt&1)*8
    //   V: (t>>3)&3 = (mt*2 + (quad>>1))&3, t&7 = (quad&1)*4 + r
    u16* outb = mat == 0 ? Qb : (mat == 1 ? Kb : Vb);
    const size_t bh = (size_t)(m0 >> 11) * NH + ((n0 + wc) >> 6);
    const int tq = (m0 & 2047) + wr;                // quadrant first row in batch
    u16* stage = sh + w * 2048;                     // per-wave 4KB

#pragma unroll
    for (int p = 0; p < 2; p++) {
#pragma unroll
        for (int mt = 0; mt < 4; mt++) {
#pragma unroll
            for (int ntl = 0; ntl < 2; ntl++) {
                const int nt = p * 2 + ntl;
#pragma unroll
                for (int r = 0; r < 4; r++) {
                    const u16 val = f2b(acc[mt][nt][r]);
                    int a;
                    if (mat == 0) {
                        a = mt * 512
                          + ((ntl * 2 + (l16 >> 3)) * 16 + quad * 4 + r) * 8 + (l16 & 7);
                    } else if (mat == 1) {
                        a = ((mt >> 1) * 2 + (quad & 1)) * 512
                          + ((ntl * 2 + (l16 >> 3)) * 16 + (quad >> 1) * 4 + (mt & 1) * 8 + r) * 8
                          + (l16 & 7);
                    } else {
                        a = ((mt >> 1) * 2 + ntl) * 512
                          + (((mt * 2 + (quad >> 1)) & 3) * 16 + l16) * 8
                          + (quad & 1) * 4 + r;
                    }
                    stage[a] = val;
                }
            }
        }
        // same-wave LDS write->read (short-typed reads alias u16 stores)
#pragma unroll
        for (int c = 0; c < 4; c++) {
            const bf16x8 vv = *(const bf16x8*)(stage + c * 512 + lane * 8);
            size_t gc;
            if (mat == 0)      gc = (bh * 128 + (tq >> 4) + c) * 2 + p;
            else if (mat == 1) gc = (bh * 64 + (tq >> 5) + (c >> 1)) * 4 + (c & 1) * 2 + p;
            else               gc = (bh * 64 + (tq >> 5) + (c >> 1)) * 4 + p * 2 + (c & 1);
            *(bf16x8*)(outb + gc * 512 + lane * 8) = vv;
        }
    }
}

// Output projection + residual: out = y @ Wo^T + x0 (fp32 out).
// Same XCD-locality remap (A-panels resident per XCD, W streamed).
__global__ __launch_bounds__(256) void gemm_wo(const u16* __restrict__ A,
        const u16* __restrict__ Wb, const float* __restrict__ X0,
        float* __restrict__ out) {
    __shared__ alignas(16) u16 As[BM * BK];
    __shared__ alignas(16) u16 Bs[BN * BK];
    const int id = blockIdx.x + 64 * blockIdx.y;   // 0..511
    const int xcd = id & 7;
    const int k = id >> 3;                          // 0..63
    const int m0 = (xcd * 8 + (k & 7)) * BM;
    const int n0 = (k >> 3) * BN;
    const int tid = threadIdx.x;
    const int w = tid >> 6;
    const int lane = tid & 63;
    const int quad = lane >> 4, l16 = lane & 15;
    const int wr = (w >> 1) * 64;
    const int wc = (w & 1) * 64;

    const int c0 = w * 2;
    const int srow = c0 * 16 + (lane >> 2);
    const int scol = (lane & 3) * 8;
    const u16* ag = A  + (size_t)(m0 + srow) * DM + scol;
    const u16* bg = Wb + (size_t)(n0 + srow) * DM + scol;
    u16* as0 = As + c0 * 512;
    u16* bs0 = Bs + c0 * 512;

    f32x4 acc[4][4];
#pragma unroll
    for (int i = 0; i < 4; i++)
#pragma unroll
        for (int j = 0; j < 4; j++) acc[i][j] = (f32x4){0.f, 0.f, 0.f, 0.f};

    for (int k0 = 0; k0 < DM; k0 += BK) {
        __builtin_amdgcn_global_load_lds((g_void*)(ag + k0),            (lds_void*)as0,         16, 0, 0);
        __builtin_amdgcn_global_load_lds((g_void*)(ag + k0 + 16 * DM),  (lds_void*)(as0 + 512), 16, 0, 0);
        __builtin_amdgcn_global_load_lds((g_void*)(bg + k0),            (lds_void*)bs0,         16, 0, 0);
        __builtin_amdgcn_global_load_lds((g_void*)(bg + k0 + 16 * DM),  (lds_void*)(bs0 + 512), 16, 0, 0);
        __syncthreads();
        bf16x8 af[4], bfr[4];
#pragma unroll
        for (int mt = 0; mt < 4; mt++)
            af[mt] = *(const bf16x8*)(As + (wr + mt * 16 + l16) * BK + quad * 8);
#pragma unroll
        for (int nt = 0; nt < 4; nt++)
            bfr[nt] = *(const bf16x8*)(Bs + (wc + nt * 16 + l16) * BK + quad * 8);
#pragma unroll
        for (int mt = 0; mt < 4; mt++)
#pragma unroll
            for (int nt = 0; nt < 4; nt++)
                acc[mt][nt] = __builtin_amdgcn_mfma_f32_16x16x32_bf16(af[mt], bfr[nt], acc[mt][nt], 0, 0, 0);
        __syncthreads();
    }

#pragma unroll
    for (int mt = 0; mt < 4; mt++) {
#pragma unroll
        for (int nt = 0; nt < 4; nt++) {
#pragma unroll
            for (int r = 0; r < 4; r++) {
                const int row = m0 + wr + mt * 16 + quad * 4 + r;
                const int col = n0 + wc + nt * 16 + l16;
                const size_t idx = (size_t)row * DM + col;
                out[idx] = acc[mt][nt][r] + X0[idx];
            }
        }
    }
}

// ---------------- Flash attention: frag-major operands, in-register P ------------
// grid (16, B*H), 512 threads = 8 waves: rg = w&3 picks the 16-q-row group,
// jg = w>>2 picks the j-interleave (j0 = jg*32, stride 64). Paired tiles
// {p, 31-p} -> identical work per block. XCD remap: 8 bh per XCD (L2-resident KV).
//
// All Q/K/V loads are base + lane*16B from the frag-major layouts written by
// gemm_qkv: 1KB fully-coalesced wave loads (was: 16-segment gathers that
// saturated the TA/TCP request path -> rounds 1-4 pinned at ~250us regardless
// of occupancy or data residency).
//
// Swapped QK^T (S = mfma(K, Q)) keeps P entirely in registers. Fixed max FM=8
// makes softmax additive over j-slices: jg partials combine as o += o',
// oL += oL' (one LDS exchange per tile, no rescale).
__global__ __launch_bounds__(512, 8) void attn_kernel(const u16* __restrict__ Q,
        const u16* __restrict__ K, const u16* __restrict__ Vt,
        const float* __restrict__ rel, u16* __restrict__ y) {
    const int id = blockIdx.x + 16 * blockIdx.y;    // 0..1023
    const int xcd = id & 7;
    const int idx = id >> 3;                        // 0..127
    const int bh = xcd * 8 + (idx & 7);             // 8 bh per XCD
    const int p = idx >> 3;                         // 0..15
    const int h = bh & (NH - 1);
    const int b = bh >> 4;
    const int tid = threadIdx.x;
    const int w = tid >> 6, lane = tid & 63;
    const int rg = w & 3, jg = w >> 2;
    const int quad = lane >> 4, l16 = lane & 15;

    __shared__ alignas(16) float rel_s[NREL];
    __shared__ alignas(16) f32x4 cb[4][5][64];      // 20 KB combine buffer
    if (tid < NREL) rel_s[tid] = rel[h * NREL + tid];
    __syncthreads();
    const float r128 = rel_s[128];

    const u16* Qh = Q  + (size_t)bh * TSEQ * DH;    // frag-major regions
    const u16* Kh = K  + (size_t)bh * TSEQ * DH;
    const u16* Vh = Vt + (size_t)bh * TSEQ * DH;

    bf16x8 ones;
#pragma unroll
    for (int j = 0; j < 8; j++) ones[j] = (short)0x3F80;

    for (int ti = 0; ti < 2; ti++) {
        const int qt = ti ? (31 - p) : p;
        const int wq = qt * 64 + rg * 16;           // wave group's first q row
        const int gq = wq + l16;                    // this lane's q row
        const u16* qb = Qh + (size_t)(wq >> 4) * 1024 + lane * 8;
        const bf16x8 qf0 = *(const bf16x8*)(qb);
        const bf16x8 qf1 = *(const bf16x8*)(qb + 512);

        f32x4 o[4];
#pragma unroll
        for (int i = 0; i < 4; i++) o[i] = (f32x4){0.f, 0.f, 0.f, 0.f};
        f32x4 oL = (f32x4){0.f, 0.f, 0.f, 0.f};
        const int jend = wq + 16;                   // wave-local causal bound

        for (int j0 = jg * 32; j0 < jend; j0 += 64) {
            const u16* kb = Kh + (size_t)(j0 >> 5) * 2048 + lane * 8;
            const bf16x8 k00 = *(const bf16x8*)(kb);
            const bf16x8 k01 = *(const bf16x8*)(kb + 512);
            const bf16x8 k10 = *(const bf16x8*)(kb + 1024);
            const bf16x8 k11 = *(const bf16x8*)(kb + 1536);
            f32x4 s0 = (f32x4){0.f, 0.f, 0.f, 0.f};
            f32x4 s1 = (f32x4){0.f, 0.f, 0.f, 0.f};
            s0 = __builtin_amdgcn_mfma_f32_16x16x32_bf16(k00, qf0, s0, 0, 0, 0);
            s0 = __builtin_amdgcn_mfma_f32_16x16x32_bf16(k01, qf1, s0, 0, 0, 0);
            s1 = __builtin_amdgcn_mfma_f32_16x16x32_bf16(k10, qf0, s1, 0, 0, 0);
            s1 = __builtin_amdgcn_mfma_f32_16x16x32_bf16(k11, qf1, s1, 0, 0, 0);
            // lane holds S[j][q=gq]; s0[r]: j = j0+8*quad+r; s1[r]: j += 4

            float p0[4], p1[4];
            const int dq = gq - j0 - 8 * quad;      // dist for s0[r] is dq - r
            if (j0 + 159 < wq) {
                // fast path: every dist in tile > 128 -> bias = rel[128], no mask
#pragma unroll
                for (int r = 0; r < 4; r++) {
                    p0[r] = __expf(s0[r] + (r128 - FIXMAX));
                    p1[r] = __expf(s1[r] + (r128 - FIXMAX));
                }
            } else {
#pragma unroll
                for (int r = 0; r < 4; r++) {
                    const int d0 = dq - r;
                    const int d1 = dq - 4 - r;
                    const int c0 = d0 < 0 ? 0 : (d0 > 128 ? 128 : d0);
                    const int c1 = d1 < 0 ? 0 : (d1 > 128 ? 128 : d1);
                    float sv0 = s0[r] + rel_s[c0];
                    float sv1 = s1[r] + rel_s[c1];
                    sv0 = d0 >= 0 ? sv0 : NEGBIG;
                    sv1 = d1 >= 0 ? sv1 : NEGBIG;
                    p0[r] = __expf(sv0 - FIXMAX);   // masked -> exp(-huge) = 0
                    p1[r] = __expf(sv1 - FIXMAX);
                }
            }
            bf16x8 pf;                              // A-frag: k = quad*8 + e
            pf[0] = (short)f2b(p0[0]); pf[1] = (short)f2b(p0[1]);
            pf[2] = (short)f2b(p0[2]); pf[3] = (short)f2b(p0[3]);
            pf[4] = (short)f2b(p1[0]); pf[5] = (short)f2b(p1[1]);
            pf[6] = (short)f2b(p1[2]); pf[7] = (short)f2b(p1[3]);

            const u16* vb = Vh + (size_t)(j0 >> 5) * 2048 + lane * 8;
            bf16x8 vf[4];
#pragma unroll
            for (int dt = 0; dt < 4; dt++)
                vf[dt] = *(const bf16x8*)(vb + dt * 512);
#pragma unroll
            for (int dt = 0; dt < 4; dt++)
                o[dt] = __builtin_amdgcn_mfma_f32_16x16x32_bf16(pf, vf[dt], o[dt], 0, 0, 0);
            oL = __builtin_amdgcn_mfma_f32_16x16x32_bf16(pf, ones, oL, 0, 0, 0);
        }

        if (jg == 1) {
#pragma unroll
            for (int dt = 0; dt < 4; dt++) cb[rg][dt][lane] = o[dt];
            cb[rg][4][lane] = oL;
        }
        __syncthreads();
        if (jg == 0) {
#pragma unroll
            for (int dt = 0; dt < 4; dt++) {
                const f32x4 op = cb[rg][dt][lane];
                o[dt].x += op.x; o[dt].y += op.y; o[dt].z += op.z; o[dt].w += op.w;
            }
            const f32x4 oLp = cb[rg][4][lane];
            oL.x += oLp.x; oL.y += oLp.y; oL.z += oLp.z; oL.w += oLp.w;
#pragma unroll
            for (int dt = 0; dt < 4; dt++) {
#pragma unroll
                for (int r = 0; r < 4; r++) {
                    const float val = o[dt][r] / oL[r];
                    const int t = wq + quad * 4 + r;
                    y[((size_t)(b * TSEQ + t)) * DM + h * DH + dt * 16 + l16] = f2b(val);
                }
            }
        }
        __syncthreads();   // cb reused by next ti
    }
}

extern "C" void kernel_launch(void* const* d_in, const int* in_sizes, int n_in,
                              void* d_out, int out_size, void* d_ws, size_t ws_size,
                              hipStream_t stream) {
    const float* x   = (const float*)d_in[0];
    const float* Wq  = (const float*)d_in[1];
    const float* Wk  = (const float*)d_in[2];
    const float* Wv  = (const float*)d_in[3];
    const float* Wo  = (const float*)d_in[4];
    const float* rel = (const float*)d_in[5];
    const float* gam = (const float*)d_in[6];
    const float* bet = (const float*)d_in[7];
    u16* ws = (u16*)d_ws;
    const size_t SZ = (size_t)BATCH * TSEQ * DM;
    const size_t need_bytes = 4 * SZ * sizeof(u16);

    if (n_in != 8) {
        fill_kernel<<<4096, 256, 0, stream>>>((float*)d_out, out_size, 8000.0f);
        return;
    }
    if (ws_size < need_bytes) {
        fill_kernel<<<4096, 256, 0, stream>>>((float*)d_out, out_size, 9500.0f);
        return;
    }

    u16* xn = ws;             // [B*T, D] normalized input (bf16)
    u16* Qb = ws + SZ;        // bf16 frag-major Q (pre-scaled by 1/8 via Wq)
    u16* Kb = ws + 2 * SZ;    // bf16 frag-major K
    u16* Vb = ws + 3 * SZ;    // bf16 frag-major V
    u16* y  = xn;             // attention output reuses xn region

    // bf16 weight scratch lives in d_out (33.5 MB; only written by the final
    // GEMM): [0,2MB) Wq*0.125, [2,4MB) Wk, [4,6MB) Wv. Wo-bf16 goes into Qb
    // after attn frees it.
    u16* wscr = (u16*)d_out;
    const int W4 = (DM * DM) / 4;   // 2^18 vec4 per matrix

    ln_kernel<<<BATCH * TSEQ, 256, 0, stream>>>(x, gam, bet, xn);
    cvt3_kernel<<<3 * W4 / 256, 256, 0, stream>>>(Wq, Wk, Wv, wscr);
    gemm_qkv<<<dim3(BATCH * TSEQ / BM, 24), 256, 0, stream>>>(xn, wscr, Qb, Kb, Vb);
    attn_kernel<<<dim3(16, BATCH * NH), 512, 0, stream>>>(Qb, Kb, Vb, rel, y);
    cvt1_kernel<<<W4 / 256, 256, 0, stream>>>(Wo, Qb, W4);   // Qb free after attn
    gemm_wo<<<dim3(BATCH * TSEQ / BM, DM / BN), 256, 0, stream>>>(y, Qb, x, (float*)d_out);
}

// Round 7
// 286.655 us; speedup vs baseline: 1.5897x; 1.0133x over previous
//
#include <hip/hip_runtime.h>
#include <math.h>

#define TSEQ 2048
#define BATCH 4
#define NH 16
#define DH 64
#define DM 1024
#define NREL 129
#define NEGBIG (-1.0e30f)
#define FIXMAX 8.0f

typedef unsigned short u16;
typedef unsigned int u32;
typedef __attribute__((ext_vector_type(8))) short bf16x8;
typedef __attribute__((ext_vector_type(4))) float f32x4;
typedef __attribute__((ext_vector_type(4))) unsigned short u16x4;

typedef __attribute__((address_space(3))) void lds_void;
typedef const __attribute__((address_space(1))) void g_void;

__device__ inline u16 f2b(float f) {
    union { float f; u32 i; } c; c.f = f;
    u32 x = c.i;
    return (u16)((x + 0x7fffu + ((x >> 16) & 1u)) >> 16);
}

// packed RNE f32->bf16 pair: D.lo = bf16(lo), D.hi = bf16(hi).
// Bit-identical to f2b for positive normal/zero inputs (both RNE).
__device__ inline u32 cvtpk(float lo, float hi) {
    u32 r;
    asm("v_cvt_pk_bf16_f32 %0, %1, %2" : "=v"(r) : "v"(lo), "v"(hi));
    return r;
}

__global__ __launch_bounds__(256) void fill_kernel(float* __restrict__ out, int n, float v) {
    for (int i = blockIdx.x * 256 + threadIdx.x; i < n; i += gridDim.x * 256)
        out[i] = v;
}

// ---------------- LayerNorm: fp32 in -> bf16 out, one block per row ----------------
__global__ __launch_bounds__(256) void ln_kernel(const float* __restrict__ x,
        const float* __restrict__ gamma, const float* __restrict__ beta,
        u16* __restrict__ xn) {
    const int row = blockIdx.x;
    const int tid = threadIdx.x;
    const float* xr = x + (size_t)row * DM;
    f32x4 xv = *(const f32x4*)(xr + tid * 4);
    float s = xv.x + xv.y + xv.z + xv.w;
    float s2 = xv.x*xv.x + xv.y*xv.y + xv.z*xv.z + xv.w*xv.w;
#pragma unroll
    for (int off = 32; off > 0; off >>= 1) {
        s  += __shfl_down(s, off, 64);
        s2 += __shfl_down(s2, off, 64);
    }
    __shared__ alignas(16) float red[8];
    const int wv = tid >> 6, ln = tid & 63;
    if (ln == 0) { red[wv] = s; red[4 + wv] = s2; }
    __syncthreads();
    s  = red[0] + red[1] + red[2] + red[3];
    s2 = red[4] + red[5] + red[6] + red[7];
    const float mu = s * (1.0f / DM);
    float var = s2 * (1.0f / DM) - mu * mu;
    var = var > 0.0f ? var : 0.0f;
    const float rstd = rsqrtf(var + 1e-5f);
    f32x4 gv = *(const f32x4*)(gamma + tid * 4);
    f32x4 bv = *(const f32x4*)(beta + tid * 4);
    u16x4 ov;
    ov.x = f2b((xv.x - mu) * rstd * gv.x + bv.x);
    ov.y = f2b((xv.y - mu) * rstd * gv.y + bv.y);
    ov.z = f2b((xv.z - mu) * rstd * gv.z + bv.z);
    ov.w = f2b((xv.w - mu) * rstd * gv.w + bv.w);
    *(u16x4*)(xn + (size_t)row * DM + tid * 4) = ov;
}

// ---------------- Weight conversion: fp32 -> bf16, done ONCE ----------------
__global__ __launch_bounds__(256) void cvt3_kernel(const float* __restrict__ a,
        const float* __restrict__ b, const float* __restrict__ c,
        u16* __restrict__ dst) {
    const int i = blockIdx.x * 256 + threadIdx.x;      // vec4 index, [0, 3*2^18)
    const int m = i >> 18;                              // 2^18 vec4 per 1024x1024
    const int j = i & 0x3FFFF;
    const float* src = m == 0 ? a : (m == 1 ? b : c);
    const float scale = m == 0 ? 0.125f : 1.0f;
    f32x4 v = *(const f32x4*)(src + (size_t)j * 4);
    u16x4 o;
    o.x = f2b(v.x * scale); o.y = f2b(v.y * scale);
    o.z = f2b(v.z * scale); o.w = f2b(v.w * scale);
    *(u16x4*)(dst + (size_t)i * 4) = o;
}

__global__ __launch_bounds__(256) void cvt1_kernel(const float* __restrict__ src,
        u16* __restrict__ dst, int n4) {
    const int i = blockIdx.x * 256 + threadIdx.x;
    if (i >= n4) return;
    f32x4 v = *(const f32x4*)(src + (size_t)i * 4);
    u16x4 o;
    o.x = f2b(v.x); o.y = f2b(v.y); o.z = f2b(v.z); o.w = f2b(v.w);
    *(u16x4*)(dst + (size_t)i * 4) = o;
}

// ---------------- GEMM: 128x128 tile, BK=32, 2-phase double-buffered LDS --------
// T3-minimum schedule: issue next tile's global_load_lds BEFORE computing the
// current one; the vmcnt drain at the end-of-iter barrier then lands after the
// MFMA cluster instead of before it (old: stage->barrier = unhidden latency).
// LDS 2x16KB = 32KB: free, VGPR=100 already caps residency at 5 blocks/CU.
#define BM 128
#define BN 128
#define BK 32

// Fragment-major layouts for attention operands (pure permutations of Q/K/V).
// Qf: per bh, per 16-q block: 2 chunks (d 0-31, 32-63) of 512 u16;
//     (t,d) -> chunk (d>>5), slot = ((d>>3)&3)*16 + (t&15), e = d&7.
// Kf: per bh, per 32-j block: 4 chunks {k00,k01,k10,k11}:
//     jr=j&31: hi=(jr>>2)&1, lk=(jr&3)|((jr>>3)<<2); chunk = hi*2 + (d>>5);
//     slot = ((d>>3)&3)*16 + lk, e = d&7.
// Vf: per bh, per 32-j block: 4 chunks dt=d>>4:
//     slot = ((t>>3)&3)*16 + (d&15), e = t&7.
__global__ __launch_bounds__(256) void gemm_qkv(const u16* __restrict__ A,
        const u16* __restrict__ W3, u16* __restrict__ Qb, u16* __restrict__ Kb,
        u16* __restrict__ Vb) {
    __shared__ alignas(16) u16 sh[16384];   // A dbuf [2][4096] + B dbuf [2][4096]
    const int id = blockIdx.x + 64 * blockIdx.y;   // 0..1535
    const int xcd = id & 7;
    const int k = id >> 3;                          // 0..191
    const int xv = xcd * 8 + (k & 7);               // m-panel: 8 per XCD
    const int yv = k >> 3;                          // 0..23 (mat, n-panel)
    const int m0 = xv * BM;
    const int mat = yv >> 3;
    const int n0 = (yv & 7) * BN;
    const u16* Wb = W3 + (size_t)mat * DM * DM;
    const int tid = threadIdx.x;
    const int w = tid >> 6;
    const int lane = tid & 63;
    const int quad = lane >> 4, l16 = lane & 15;
    const int wr = (w >> 1) * 64;
    const int wc = (w & 1) * 64;

    const int c0 = w * 2;
    const int srow = c0 * 16 + (lane >> 2);
    const int scol = (lane & 3) * 8;
    const u16* ag = A  + (size_t)(m0 + srow) * DM + scol;
    const u16* bg = Wb + (size_t)(n0 + srow) * DM + scol;
    u16* asw = sh + c0 * 512;           // + buf*4096
    u16* bsw = sh + 8192 + c0 * 512;    // + buf*4096

    f32x4 acc[4][4];
#pragma unroll
    for (int i = 0; i < 4; i++)
#pragma unroll
        for (int j = 0; j < 4; j++) acc[i][j] = (f32x4){0.f, 0.f, 0.f, 0.f};

#define QKV_STAGE(buf, kk) do { \
    __builtin_amdgcn_global_load_lds((g_void*)(ag + (kk)),            (lds_void*)(asw + (buf)*4096),       16, 0, 0); \
    __builtin_amdgcn_global_load_lds((g_void*)(ag + (kk) + 16 * DM),  (lds_void*)(asw + (buf)*4096 + 512), 16, 0, 0); \
    __builtin_amdgcn_global_load_lds((g_void*)(bg + (kk)),            (lds_void*)(bsw + (buf)*4096),       16, 0, 0); \
    __builtin_amdgcn_global_load_lds((g_void*)(bg + (kk) + 16 * DM),  (lds_void*)(bsw + (buf)*4096 + 512), 16, 0, 0); \
} while (0)

    QKV_STAGE(0, 0);
    __syncthreads();
    for (int k0 = 0; k0 < DM; k0 += BK) {
        const int cur = (k0 >> 5) & 1;
        if (k0 + BK < DM) QKV_STAGE(cur ^ 1, k0 + BK);
        const u16* Ac = sh + cur * 4096;
        const u16* Bc = sh + 8192 + cur * 4096;
        bf16x8 af[4], bfr[4];
#pragma unroll
        for (int mt = 0; mt < 4; mt++)
            af[mt] = *(const bf16x8*)(Ac + (wr + mt * 16 + l16) * BK + quad * 8);
#pragma unroll
        for (int nt = 0; nt < 4; nt++)
            bfr[nt] = *(const bf16x8*)(Bc + (wc + nt * 16 + l16) * BK + quad * 8);
#pragma unroll
        for (int mt = 0; mt < 4; mt++)
#pragma unroll
            for (int nt = 0; nt < 4; nt++)
                acc[mt][nt] = __builtin_amdgcn_mfma_f32_16x16x32_bf16(af[mt], bfr[nt], acc[mt][nt], 0, 0, 0);
        __syncthreads();   // drains next-tile loads (after MFMA cover) + read fence
    }
#undef QKV_STAGE

    // ---- Epilogue: per-wave 4KB LDS staging -> coalesced 1KB chunk stores ----
    u16* outb = mat == 0 ? Qb : (mat == 1 ? Kb : Vb);
    const size_t bh = (size_t)(m0 >> 11) * NH + ((n0 + wc) >> 6);
    const int tq = (m0 & 2047) + wr;                // quadrant first row in batch
    u16* stage = sh + w * 2048;                     // per-wave 4KB (buffers dead now)

#pragma unroll
    for (int p = 0; p < 2; p++) {
#pragma unroll
        for (int mt = 0; mt < 4; mt++) {
#pragma unroll
            for (int ntl = 0; ntl < 2; ntl++) {
                const int nt = p * 2 + ntl;
#pragma unroll
                for (int r = 0; r < 4; r++) {
                    const u16 val = f2b(acc[mt][nt][r]);
                    int a;
                    if (mat == 0) {
                        a = mt * 512
                          + ((ntl * 2 + (l16 >> 3)) * 16 + quad * 4 + r) * 8 + (l16 & 7);
                    } else if (mat == 1) {
                        a = ((mt >> 1) * 2 + (quad & 1)) * 512
                          + ((ntl * 2 + (l16 >> 3)) * 16 + (quad >> 1) * 4 + (mt & 1) * 8 + r) * 8
                          + (l16 & 7);
                    } else {
                        a = ((mt >> 1) * 2 + ntl) * 512
                          + (((mt * 2 + (quad >> 1)) & 3) * 16 + l16) * 8
                          + (quad & 1) * 4 + r;
                    }
                    stage[a] = val;
                }
            }
        }
        // same-wave LDS write->read (short-typed reads alias u16 stores)
#pragma unroll
        for (int c = 0; c < 4; c++) {
            const bf16x8 vv = *(const bf16x8*)(stage + c * 512 + lane * 8);
            size_t gc;
            if (mat == 0)      gc = (bh * 128 + (tq >> 4) + c) * 2 + p;
            else if (mat == 1) gc = (bh * 64 + (tq >> 5) + (c >> 1)) * 4 + (c & 1) * 2 + p;
            else               gc = (bh * 64 + (tq >> 5) + (c >> 1)) * 4 + p * 2 + (c & 1);
            *(bf16x8*)(outb + gc * 512 + lane * 8) = vv;
        }
    }
}

// Output projection + residual: out = y @ Wo^T + x0 (fp32 out).
// Same XCD remap; same 2-phase double-buffered schedule.
__global__ __launch_bounds__(256) void gemm_wo(const u16* __restrict__ A,
        const u16* __restrict__ Wb, const float* __restrict__ X0,
        float* __restrict__ out) {
    __shared__ alignas(16) u16 sh[16384];
    const int id = blockIdx.x + 64 * blockIdx.y;   // 0..511
    const int xcd = id & 7;
    const int k = id >> 3;                          // 0..63
    const int m0 = (xcd * 8 + (k & 7)) * BM;
    const int n0 = (k >> 3) * BN;
    const int tid = threadIdx.x;
    const int w = tid >> 6;
    const int lane = tid & 63;
    const int quad = lane >> 4, l16 = lane & 15;
    const int wr = (w >> 1) * 64;
    const int wc = (w & 1) * 64;

    const int c0 = w * 2;
    const int srow = c0 * 16 + (lane >> 2);
    const int scol = (lane & 3) * 8;
    const u16* ag = A  + (size_t)(m0 + srow) * DM + scol;
    const u16* bg = Wb + (size_t)(n0 + srow) * DM + scol;
    u16* asw = sh + c0 * 512;
    u16* bsw = sh + 8192 + c0 * 512;

    f32x4 acc[4][4];
#pragma unroll
    for (int i = 0; i < 4; i++)
#pragma unroll
        for (int j = 0; j < 4; j++) acc[i][j] = (f32x4){0.f, 0.f, 0.f, 0.f};

#define WO_STAGE(buf, kk) do { \
    __builtin_amdgcn_global_load_lds((g_void*)(ag + (kk)),            (lds_void*)(asw + (buf)*4096),       16, 0, 0); \
    __builtin_amdgcn_global_load_lds((g_void*)(ag + (kk) + 16 * DM),  (lds_void*)(asw + (buf)*4096 + 512), 16, 0, 0); \
    __builtin_amdgcn_global_load_lds((g_void*)(bg + (kk)),            (lds_void*)(bsw + (buf)*4096),       16, 0, 0); \
    __builtin_amdgcn_global_load_lds((g_void*)(bg + (kk) + 16 * DM),  (lds_void*)(bsw + (buf)*4096 + 512), 16, 0, 0); \
} while (0)

    WO_STAGE(0, 0);
    __syncthreads();
    for (int k0 = 0; k0 < DM; k0 += BK) {
        const int cur = (k0 >> 5) & 1;
        if (k0 + BK < DM) WO_STAGE(cur ^ 1, k0 + BK);
        const u16* Ac = sh + cur * 4096;
        const u16* Bc = sh + 8192 + cur * 4096;
        bf16x8 af[4], bfr[4];
#pragma unroll
        for (int mt = 0; mt < 4; mt++)
            af[mt] = *(const bf16x8*)(Ac + (wr + mt * 16 + l16) * BK + quad * 8);
#pragma unroll
        for (int nt = 0; nt < 4; nt++)
            bfr[nt] = *(const bf16x8*)(Bc + (wc + nt * 16 + l16) * BK + quad * 8);
#pragma unroll
        for (int mt = 0; mt < 4; mt++)
#pragma unroll
            for (int nt = 0; nt < 4; nt++)
                acc[mt][nt] = __builtin_amdgcn_mfma_f32_16x16x32_bf16(af[mt], bfr[nt], acc[mt][nt], 0, 0, 0);
        __syncthreads();
    }
#undef WO_STAGE

#pragma unroll
    for (int mt = 0; mt < 4; mt++) {
#pragma unroll
        for (int nt = 0; nt < 4; nt++) {
#pragma unroll
            for (int r = 0; r < 4; r++) {
                const int row = m0 + wr + mt * 16 + quad * 4 + r;
                const int col = n0 + wc + nt * 16 + l16;
                const size_t idx = (size_t)row * DM + col;
                out[idx] = acc[mt][nt][r] + X0[idx];
            }
        }
    }
}

// ---------------- Flash attention: frag-major operands, in-register P ------------
// grid (16, B*H), 512 threads = 8 waves: rg = w&3 (16-q-row group), jg = w>>2
// (j-interleave, stride 64). Paired tiles {p, 31-p}. XCD remap: 8 bh per XCD.
// All Q/K/V loads are base + lane*16B (coalesced 1KB wave loads).
// Swapped QK^T keeps P in registers; P-pack via v_cvt_pk_bf16_f32 (4 ops vs
// 24 f2b ops). y-store staged through LDS -> 2 coalesced 1KB stores per tile
// (was 16x 4-segment scatters).
__global__ __launch_bounds__(512, 8) void attn_kernel(const u16* __restrict__ Q,
        const u16* __restrict__ K, const u16* __restrict__ Vt,
        const float* __restrict__ rel, u16* __restrict__ y) {
    const int id = blockIdx.x + 16 * blockIdx.y;    // 0..1023
    const int xcd = id & 7;
    const int idx = id >> 3;                        // 0..127
    const int bh = xcd * 8 + (idx & 7);             // 8 bh per XCD
    const int p = idx >> 3;                         // 0..15
    const int h = bh & (NH - 1);
    const int b = bh >> 4;
    const int tid = threadIdx.x;
    const int w = tid >> 6, lane = tid & 63;
    const int rg = w & 3, jg = w >> 2;
    const int quad = lane >> 4, l16 = lane & 15;

    __shared__ alignas(16) float rel_s[NREL];
    __shared__ alignas(16) f32x4 cb[4][5][64];      // 20 KB combine buffer
    __shared__ alignas(16) u16 st_s[4][1024];       // 8 KB y-store staging
    if (tid < NREL) rel_s[tid] = rel[h * NREL + tid];
    __syncthreads();
    const float r128 = rel_s[128];

    const u16* Qh = Q  + (size_t)bh * TSEQ * DH;    // frag-major regions
    const u16* Kh = K  + (size_t)bh * TSEQ * DH;
    const u16* Vh = Vt + (size_t)bh * TSEQ * DH;

    bf16x8 ones;
#pragma unroll
    for (int j = 0; j < 8; j++) ones[j] = (short)0x3F80;

    for (int ti = 0; ti < 2; ti++) {
        const int qt = ti ? (31 - p) : p;
        const int wq = qt * 64 + rg * 16;           // wave group's first q row
        const int gq = wq + l16;                    // this lane's q row
        const u16* qb = Qh + (size_t)(wq >> 4) * 1024 + lane * 8;
        const bf16x8 qf0 = *(const bf16x8*)(qb);
        const bf16x8 qf1 = *(const bf16x8*)(qb + 512);

        f32x4 o[4];
#pragma unroll
        for (int i = 0; i < 4; i++) o[i] = (f32x4){0.f, 0.f, 0.f, 0.f};
        f32x4 oL = (f32x4){0.f, 0.f, 0.f, 0.f};
        const int jend = wq + 16;                   // wave-local causal bound

        for (int j0 = jg * 32; j0 < jend; j0 += 64) {
            const u16* kb = Kh + (size_t)(j0 >> 5) * 2048 + lane * 8;
            const bf16x8 k00 = *(const bf16x8*)(kb);
            const bf16x8 k01 = *(const bf16x8*)(kb + 512);
            const bf16x8 k10 = *(const bf16x8*)(kb + 1024);
            const bf16x8 k11 = *(const bf16x8*)(kb + 1536);
            f32x4 s0 = (f32x4){0.f, 0.f, 0.f, 0.f};
            f32x4 s1 = (f32x4){0.f, 0.f, 0.f, 0.f};
            s0 = __builtin_amdgcn_mfma_f32_16x16x32_bf16(k00, qf0, s0, 0, 0, 0);
            s0 = __builtin_amdgcn_mfma_f32_16x16x32_bf16(k01, qf1, s0, 0, 0, 0);
            s1 = __builtin_amdgcn_mfma_f32_16x16x32_bf16(k10, qf0, s1, 0, 0, 0);
            s1 = __builtin_amdgcn_mfma_f32_16x16x32_bf16(k11, qf1, s1, 0, 0, 0);
            // lane holds S[j][q=gq]; s0[r]: j = j0+8*quad+r; s1[r]: j += 4

            float p0[4], p1[4];
            const int dq = gq - j0 - 8 * quad;      // dist for s0[r] is dq - r
            if (j0 + 159 < wq) {
                // fast path: every dist in tile > 128 -> bias = rel[128], no mask
#pragma unroll
                for (int r = 0; r < 4; r++) {
                    p0[r] = __expf(s0[r] + (r128 - FIXMAX));
                    p1[r] = __expf(s1[r] + (r128 - FIXMAX));
                }
            } else {
#pragma unroll
                for (int r = 0; r < 4; r++) {
                    const int d0 = dq - r;
                    const int d1 = dq - 4 - r;
                    const int c0 = d0 < 0 ? 0 : (d0 > 128 ? 128 : d0);
                    const int c1 = d1 < 0 ? 0 : (d1 > 128 ? 128 : d1);
                    float sv0 = s0[r] + rel_s[c0];
                    float sv1 = s1[r] + rel_s[c1];
                    sv0 = d0 >= 0 ? sv0 : NEGBIG;
                    sv1 = d1 >= 0 ? sv1 : NEGBIG;
                    p0[r] = __expf(sv0 - FIXMAX);   // masked -> exp(-huge) = 0
                    p1[r] = __expf(sv1 - FIXMAX);
                }
            }
            union { u32 u[4]; bf16x8 v; } pk_;      // A-frag: k = quad*8 + e
            pk_.u[0] = cvtpk(p0[0], p0[1]);
            pk_.u[1] = cvtpk(p0[2], p0[3]);
            pk_.u[2] = cvtpk(p1[0], p1[1]);
            pk_.u[3] = cvtpk(p1[2], p1[3]);
            const bf16x8 pf = pk_.v;

            const u16* vb = Vh + (size_t)(j0 >> 5) * 2048 + lane * 8;
            bf16x8 vf[4];
#pragma unroll
            for (int dt = 0; dt < 4; dt++)
                vf[dt] = *(const bf16x8*)(vb + dt * 512);
#pragma unroll
            for (int dt = 0; dt < 4; dt++)
                o[dt] = __builtin_amdgcn_mfma_f32_16x16x32_bf16(pf, vf[dt], o[dt], 0, 0, 0);
            oL = __builtin_amdgcn_mfma_f32_16x16x32_bf16(pf, ones, oL, 0, 0, 0);
        }

        if (jg == 1) {
#pragma unroll
            for (int dt = 0; dt < 4; dt++) cb[rg][dt][lane] = o[dt];
            cb[rg][4][lane] = oL;
        }
        __syncthreads();
        if (jg == 0) {
#pragma unroll
            for (int dt = 0; dt < 4; dt++) {
                const f32x4 op = cb[rg][dt][lane];
                o[dt].x += op.x; o[dt].y += op.y; o[dt].z += op.z; o[dt].w += op.w;
            }
            const f32x4 oLp = cb[rg][4][lane];
            oL.x += oLp.x; oL.y += oLp.y; oL.z += oLp.z; oL.w += oLp.w;
            float inv[4];
#pragma unroll
            for (int r = 0; r < 4; r++) inv[r] = 1.0f / oL[r];
            // stage [16 rows][64 d] u16 in LDS, then 2 coalesced 1KB stores
            u16* st = st_s[rg];
#pragma unroll
            for (int dt = 0; dt < 4; dt++)
#pragma unroll
                for (int r = 0; r < 4; r++)
                    st[(quad * 4 + r) * 64 + dt * 16 + l16] = f2b(o[dt][r] * inv[r]);
#pragma unroll
            for (int ps = 0; ps < 2; ps++) {
                const bf16x8 vv = *(const bf16x8*)(st + ps * 512 + lane * 8);
                const int row = wq + ps * 8 + (lane >> 3);
                *(bf16x8*)(y + ((size_t)(b * TSEQ + row)) * DM + h * DH + (lane & 7) * 8) = vv;
            }
        }
        __syncthreads();   // cb/st reused by next ti
    }
}

extern "C" void kernel_launch(void* const* d_in, const int* in_sizes, int n_in,
                              void* d_out, int out_size, void* d_ws, size_t ws_size,
                              hipStream_t stream) {
    const float* x   = (const float*)d_in[0];
    const float* Wq  = (const float*)d_in[1];
    const float* Wk  = (const float*)d_in[2];
    const float* Wv  = (const float*)d_in[3];
    const float* Wo  = (const float*)d_in[4];
    const float* rel = (const float*)d_in[5];
    const float* gam = (const float*)d_in[6];
    const float* bet = (const float*)d_in[7];
    u16* ws = (u16*)d_ws;
    const size_t SZ = (size_t)BATCH * TSEQ * DM;
    const size_t need_bytes = 4 * SZ * sizeof(u16);

    if (n_in != 8) {
        fill_kernel<<<4096, 256, 0, stream>>>((float*)d_out, out_size, 8000.0f);
        return;
    }
    if (ws_size < need_bytes) {
        fill_kernel<<<4096, 256, 0, stream>>>((float*)d_out, out_size, 9500.0f);
        return;
    }

    u16* xn = ws;             // [B*T, D] normalized input (bf16)
    u16* Qb = ws + SZ;        // bf16 frag-major Q (pre-scaled by 1/8 via Wq)
    u16* Kb = ws + 2 * SZ;    // bf16 frag-major K
    u16* Vb = ws + 3 * SZ;    // bf16 frag-major V
    u16* y  = xn;             // attention output reuses xn region

    // bf16 weight scratch lives in d_out (33.5 MB; only written by the final
    // GEMM): [0,2MB) Wq*0.125, [2,4MB) Wk, [4,6MB) Wv. Wo-bf16 goes into Qb
    // after attn frees it.
    u16* wscr = (u16*)d_out;
    const int W4 = (DM * DM) / 4;   // 2^18 vec4 per matrix

    ln_kernel<<<BATCH * TSEQ, 256, 0, stream>>>(x, gam, bet, xn);
    cvt3_kernel<<<3 * W4 / 256, 256, 0, stream>>>(Wq, Wk, Wv, wscr);
    gemm_qkv<<<dim3(BATCH * TSEQ / BM, 24), 256, 0, stream>>>(xn, wscr, Qb, Kb, Vb);
    attn_kernel<<<dim3(16, BATCH * NH), 512, 0, stream>>>(Qb, Kb, Vb, rel, y);
    cvt1_kernel<<<W4 / 256, 256, 0, stream>>>(Wo, Qb, W4);   // Qb free after attn
    gemm_wo<<<dim3(BATCH * TSEQ / BM, DM / BN), 256, 0, stream>>>(y, Qb, x, (float*)d_out);
}

// Round 8
// 265.502 us; speedup vs baseline: 1.7164x; 1.0797x over previous
//
#include <hip/hip_runtime.h>
#include <math.h>

#define TSEQ 2048
#define BATCH 4
#define NH 16
#define DH 64
#define DM 1024
#define NREL 129
#define NEGBIG (-1.0e30f)
#define FIXMAX 8.0f

typedef unsigned short u16;
typedef unsigned int u32;
typedef __attribute__((ext_vector_type(8))) short bf16x8;
typedef __attribute__((ext_vector_type(4))) float f32x4;
typedef __attribute__((ext_vector_type(4))) unsigned short u16x4;

typedef __attribute__((address_space(3))) void lds_void;
typedef const __attribute__((address_space(1))) void g_void;

__device__ inline u16 f2b(float f) {
    union { float f; u32 i; } c; c.f = f;
    u32 x = c.i;
    return (u16)((x + 0x7fffu + ((x >> 16) & 1u)) >> 16);
}

// packed RNE f32->bf16 pair: D.lo = bf16(lo), D.hi = bf16(hi).
// Bit-identical to f2b for positive normal/zero inputs (both RNE).
__device__ inline u32 cvtpk(float lo, float hi) {
    u32 r;
    asm("v_cvt_pk_bf16_f32 %0, %1, %2" : "=v"(r) : "v"(lo), "v"(hi));
    return r;
}

__global__ __launch_bounds__(256) void fill_kernel(float* __restrict__ out, int n, float v) {
    for (int i = blockIdx.x * 256 + threadIdx.x; i < n; i += gridDim.x * 256)
        out[i] = v;
}

// ---------------- LayerNorm: fp32 in -> bf16 out, one block per row ----------------
__global__ __launch_bounds__(256) void ln_kernel(const float* __restrict__ x,
        const float* __restrict__ gamma, const float* __restrict__ beta,
        u16* __restrict__ xn) {
    const int row = blockIdx.x;
    const int tid = threadIdx.x;
    const float* xr = x + (size_t)row * DM;
    f32x4 xv = *(const f32x4*)(xr + tid * 4);
    float s = xv.x + xv.y + xv.z + xv.w;
    float s2 = xv.x*xv.x + xv.y*xv.y + xv.z*xv.z + xv.w*xv.w;
#pragma unroll
    for (int off = 32; off > 0; off >>= 1) {
        s  += __shfl_down(s, off, 64);
        s2 += __shfl_down(s2, off, 64);
    }
    __shared__ alignas(16) float red[8];
    const int wv = tid >> 6, ln = tid & 63;
    if (ln == 0) { red[wv] = s; red[4 + wv] = s2; }
    __syncthreads();
    s  = red[0] + red[1] + red[2] + red[3];
    s2 = red[4] + red[5] + red[6] + red[7];
    const float mu = s * (1.0f / DM);
    float var = s2 * (1.0f / DM) - mu * mu;
    var = var > 0.0f ? var : 0.0f;
    const float rstd = rsqrtf(var + 1e-5f);
    f32x4 gv = *(const f32x4*)(gamma + tid * 4);
    f32x4 bv = *(const f32x4*)(beta + tid * 4);
    u16x4 ov;
    ov.x = f2b((xv.x - mu) * rstd * gv.x + bv.x);
    ov.y = f2b((xv.y - mu) * rstd * gv.y + bv.y);
    ov.z = f2b((xv.z - mu) * rstd * gv.z + bv.z);
    ov.w = f2b((xv.w - mu) * rstd * gv.w + bv.w);
    *(u16x4*)(xn + (size_t)row * DM + tid * 4) = ov;
}

// ---------------- Weight conversion: fp32 -> bf16, done ONCE ----------------
__global__ __launch_bounds__(256) void cvt3_kernel(const float* __restrict__ a,
        const float* __restrict__ b, const float* __restrict__ c,
        u16* __restrict__ dst) {
    const int i = blockIdx.x * 256 + threadIdx.x;      // vec4 index, [0, 3*2^18)
    const int m = i >> 18;                              // 2^18 vec4 per 1024x1024
    const int j = i & 0x3FFFF;
    const float* src = m == 0 ? a : (m == 1 ? b : c);
    const float scale = m == 0 ? 0.125f : 1.0f;
    f32x4 v = *(const f32x4*)(src + (size_t)j * 4);
    u16x4 o;
    o.x = f2b(v.x * scale); o.y = f2b(v.y * scale);
    o.z = f2b(v.z * scale); o.w = f2b(v.w * scale);
    *(u16x4*)(dst + (size_t)i * 4) = o;
}

__global__ __launch_bounds__(256) void cvt1_kernel(const float* __restrict__ src,
        u16* __restrict__ dst, int n4) {
    const int i = blockIdx.x * 256 + threadIdx.x;
    if (i >= n4) return;
    f32x4 v = *(const f32x4*)(src + (size_t)i * 4);
    u16x4 o;
    o.x = f2b(v.x); o.y = f2b(v.y); o.z = f2b(v.z); o.w = f2b(v.w);
    *(u16x4*)(dst + (size_t)i * 4) = o;
}

// ---------------- GEMM: 128x128 tile, BK=32, 2-phase double-buffered LDS --------
#define BM 128
#define BN 128
#define BK 32

// Fragment-major layouts for attention operands (pure permutations of Q/K/V).
// Qf: per bh, per 16-q block: 2 chunks (d 0-31, 32-63) of 512 u16;
//     (t,d) -> chunk (d>>5), slot = ((d>>3)&3)*16 + (t&15), e = d&7.
// Kf: per bh, per 32-j block: 4 chunks {k00,k01,k10,k11}:
//     jr=j&31: hi=(jr>>2)&1, lk=(jr&3)|((jr>>3)<<2); chunk = hi*2 + (d>>5);
//     slot = ((d>>3)&3)*16 + lk, e = d&7.
// Vf: per bh, per 32-j block: 4 chunks dt=d>>4:
//     slot = ((t>>3)&3)*16 + (d&15), e = t&7.
__global__ __launch_bounds__(256) void gemm_qkv(const u16* __restrict__ A,
        const u16* __restrict__ W3, u16* __restrict__ Qb, u16* __restrict__ Kb,
        u16* __restrict__ Vb) {
    __shared__ alignas(16) u16 sh[16384];   // A dbuf [2][4096] + B dbuf [2][4096]
    const int id = blockIdx.x + 64 * blockIdx.y;   // 0..1535
    const int xcd = id & 7;
    const int k = id >> 3;                          // 0..191
    const int xv = xcd * 8 + (k & 7);               // m-panel: 8 per XCD
    const int yv = k >> 3;                          // 0..23 (mat, n-panel)
    const int m0 = xv * BM;
    const int mat = yv >> 3;
    const int n0 = (yv & 7) * BN;
    const u16* Wb = W3 + (size_t)mat * DM * DM;
    const int tid = threadIdx.x;
    const int w = tid >> 6;
    const int lane = tid & 63;
    const int quad = lane >> 4, l16 = lane & 15;
    const int wr = (w >> 1) * 64;
    const int wc = (w & 1) * 64;

    const int c0 = w * 2;
    const int srow = c0 * 16 + (lane >> 2);
    const int scol = (lane & 3) * 8;
    const u16* ag = A  + (size_t)(m0 + srow) * DM + scol;
    const u16* bg = Wb + (size_t)(n0 + srow) * DM + scol;
    u16* asw = sh + c0 * 512;           // + buf*4096
    u16* bsw = sh + 8192 + c0 * 512;    // + buf*4096

    f32x4 acc[4][4];
#pragma unroll
    for (int i = 0; i < 4; i++)
#pragma unroll
        for (int j = 0; j < 4; j++) acc[i][j] = (f32x4){0.f, 0.f, 0.f, 0.f};

#define QKV_STAGE(buf, kk) do { \
    __builtin_amdgcn_global_load_lds((g_void*)(ag + (kk)),            (lds_void*)(asw + (buf)*4096),       16, 0, 0); \
    __builtin_amdgcn_global_load_lds((g_void*)(ag + (kk) + 16 * DM),  (lds_void*)(asw + (buf)*4096 + 512), 16, 0, 0); \
    __builtin_amdgcn_global_load_lds((g_void*)(bg + (kk)),            (lds_void*)(bsw + (buf)*4096),       16, 0, 0); \
    __builtin_amdgcn_global_load_lds((g_void*)(bg + (kk) + 16 * DM),  (lds_void*)(bsw + (buf)*4096 + 512), 16, 0, 0); \
} while (0)

    QKV_STAGE(0, 0);
    __syncthreads();
    for (int k0 = 0; k0 < DM; k0 += BK) {
        const int cur = (k0 >> 5) & 1;
        if (k0 + BK < DM) QKV_STAGE(cur ^ 1, k0 + BK);
        const u16* Ac = sh + cur * 4096;
        const u16* Bc = sh + 8192 + cur * 4096;
        bf16x8 af[4], bfr[4];
#pragma unroll
        for (int mt = 0; mt < 4; mt++)
            af[mt] = *(const bf16x8*)(Ac + (wr + mt * 16 + l16) * BK + quad * 8);
#pragma unroll
        for (int nt = 0; nt < 4; nt++)
            bfr[nt] = *(const bf16x8*)(Bc + (wc + nt * 16 + l16) * BK + quad * 8);
#pragma unroll
        for (int mt = 0; mt < 4; mt++)
#pragma unroll
            for (int nt = 0; nt < 4; nt++)
                acc[mt][nt] = __builtin_amdgcn_mfma_f32_16x16x32_bf16(af[mt], bfr[nt], acc[mt][nt], 0, 0, 0);
        __syncthreads();   // drains next-tile loads (after MFMA cover) + read fence
    }
#undef QKV_STAGE

    // ---- Epilogue: per-wave 4KB LDS staging -> coalesced 1KB chunk stores ----
    u16* outb = mat == 0 ? Qb : (mat == 1 ? Kb : Vb);
    const size_t bh = (size_t)(m0 >> 11) * NH + ((n0 + wc) >> 6);
    const int tq = (m0 & 2047) + wr;                // quadrant first row in batch
    u16* stage = sh + w * 2048;                     // per-wave 4KB (buffers dead now)

#pragma unroll
    for (int p = 0; p < 2; p++) {
#pragma unroll
        for (int mt = 0; mt < 4; mt++) {
#pragma unroll
            for (int ntl = 0; ntl < 2; ntl++) {
                const int nt = p * 2 + ntl;
#pragma unroll
                for (int r = 0; r < 4; r++) {
                    const u16 val = f2b(acc[mt][nt][r]);
                    int a;
                    if (mat == 0) {
                        a = mt * 512
                          + ((ntl * 2 + (l16 >> 3)) * 16 + quad * 4 + r) * 8 + (l16 & 7);
                    } else if (mat == 1) {
                        a = ((mt >> 1) * 2 + (quad & 1)) * 512
                          + ((ntl * 2 + (l16 >> 3)) * 16 + (quad >> 1) * 4 + (mt & 1) * 8 + r) * 8
                          + (l16 & 7);
                    } else {
                        a = ((mt >> 1) * 2 + ntl) * 512
                          + (((mt * 2 + (quad >> 1)) & 3) * 16 + l16) * 8
                          + (quad & 1) * 4 + r;
                    }
                    stage[a] = val;
                }
            }
        }
        // same-wave LDS write->read (short-typed reads alias u16 stores)
#pragma unroll
        for (int c = 0; c < 4; c++) {
            const bf16x8 vv = *(const bf16x8*)(stage + c * 512 + lane * 8);
            size_t gc;
            if (mat == 0)      gc = (bh * 128 + (tq >> 4) + c) * 2 + p;
            else if (mat == 1) gc = (bh * 64 + (tq >> 5) + (c >> 1)) * 4 + (c & 1) * 2 + p;
            else               gc = (bh * 64 + (tq >> 5) + (c >> 1)) * 4 + p * 2 + (c & 1);
            *(bf16x8*)(outb + gc * 512 + lane * 8) = vv;
        }
    }
}

// Output projection + residual: out = y @ Wo^T + x0 (fp32 out).
// Same XCD remap; same 2-phase double-buffered schedule.
__global__ __launch_bounds__(256) void gemm_wo(const u16* __restrict__ A,
        const u16* __restrict__ Wb, const float* __restrict__ X0,
        float* __restrict__ out) {
    __shared__ alignas(16) u16 sh[16384];
    const int id = blockIdx.x + 64 * blockIdx.y;   // 0..511
    const int xcd = id & 7;
    const int k = id >> 3;                          // 0..63
    const int m0 = (xcd * 8 + (k & 7)) * BM;
    const int n0 = (k >> 3) * BN;
    const int tid = threadIdx.x;
    const int w = tid >> 6;
    const int lane = tid & 63;
    const int quad = lane >> 4, l16 = lane & 15;
    const int wr = (w >> 1) * 64;
    const int wc = (w & 1) * 64;

    const int c0 = w * 2;
    const int srow = c0 * 16 + (lane >> 2);
    const int scol = (lane & 3) * 8;
    const u16* ag = A  + (size_t)(m0 + srow) * DM + scol;
    const u16* bg = Wb + (size_t)(n0 + srow) * DM + scol;
    u16* asw = sh + c0 * 512;
    u16* bsw = sh + 8192 + c0 * 512;

    f32x4 acc[4][4];
#pragma unroll
    for (int i = 0; i < 4; i++)
#pragma unroll
        for (int j = 0; j < 4; j++) acc[i][j] = (f32x4){0.f, 0.f, 0.f, 0.f};

#define WO_STAGE(buf, kk) do { \
    __builtin_amdgcn_global_load_lds((g_void*)(ag + (kk)),            (lds_void*)(asw + (buf)*4096),       16, 0, 0); \
    __builtin_amdgcn_global_load_lds((g_void*)(ag + (kk) + 16 * DM),  (lds_void*)(asw + (buf)*4096 + 512), 16, 0, 0); \
    __builtin_amdgcn_global_load_lds((g_void*)(bg + (kk)),            (lds_void*)(bsw + (buf)*4096),       16, 0, 0); \
    __builtin_amdgcn_global_load_lds((g_void*)(bg + (kk) + 16 * DM),  (lds_void*)(bsw + (buf)*4096 + 512), 16, 0, 0); \
} while (0)

    WO_STAGE(0, 0);
    __syncthreads();
    for (int k0 = 0; k0 < DM; k0 += BK) {
        const int cur = (k0 >> 5) & 1;
        if (k0 + BK < DM) WO_STAGE(cur ^ 1, k0 + BK);
        const u16* Ac = sh + cur * 4096;
        const u16* Bc = sh + 8192 + cur * 4096;
        bf16x8 af[4], bfr[4];
#pragma unroll
        for (int mt = 0; mt < 4; mt++)
            af[mt] = *(const bf16x8*)(Ac + (wr + mt * 16 + l16) * BK + quad * 8);
#pragma unroll
        for (int nt = 0; nt < 4; nt++)
            bfr[nt] = *(const bf16x8*)(Bc + (wc + nt * 16 + l16) * BK + quad * 8);
#pragma unroll
        for (int mt = 0; mt < 4; mt++)
#pragma unroll
            for (int nt = 0; nt < 4; nt++)
                acc[mt][nt] = __builtin_amdgcn_mfma_f32_16x16x32_bf16(af[mt], bfr[nt], acc[mt][nt], 0, 0, 0);
        __syncthreads();
    }
#undef WO_STAGE

#pragma unroll
    for (int mt = 0; mt < 4; mt++) {
#pragma unroll
        for (int nt = 0; nt < 4; nt++) {
#pragma unroll
            for (int r = 0; r < 4; r++) {
                const int row = m0 + wr + mt * 16 + quad * 4 + r;
                const int col = n0 + wc + nt * 16 + l16;
                const size_t idx = (size_t)row * DM + col;
                out[idx] = acc[mt][nt][r] + X0[idx];
            }
        }
    }
}

// softmax + bf16-pack for one 16-row group. s0[r]: j = j0+8*quad+r; s1[r]: j += 4.
// dq = gq - j0 - 8*quad; fast <=> all dists in tile > 128.
__device__ inline bf16x8 sm_pack(f32x4 s0, f32x4 s1, int dq, bool fast,
                                 const float* rel_s, float r128) {
    float p0[4], p1[4];
    if (fast) {
#pragma unroll
        for (int r = 0; r < 4; r++) {
            p0[r] = __expf(s0[r] + (r128 - FIXMAX));
            p1[r] = __expf(s1[r] + (r128 - FIXMAX));
        }
    } else {
#pragma unroll
        for (int r = 0; r < 4; r++) {
            const int d0 = dq - r;
            const int d1 = dq - 4 - r;
            const int c0 = d0 < 0 ? 0 : (d0 > 128 ? 128 : d0);
            const int c1 = d1 < 0 ? 0 : (d1 > 128 ? 128 : d1);
            float sv0 = s0[r] + rel_s[c0];
            float sv1 = s1[r] + rel_s[c1];
            sv0 = d0 >= 0 ? sv0 : NEGBIG;
            sv1 = d1 >= 0 ? sv1 : NEGBIG;
            p0[r] = __expf(sv0 - FIXMAX);   // masked -> exp(-huge) = 0
            p1[r] = __expf(sv1 - FIXMAX);
        }
    }
    union { u32 u[4]; bf16x8 v; } pk_;      // A-frag: k = quad*8 + e
    pk_.u[0] = cvtpk(p0[0], p0[1]);
    pk_.u[1] = cvtpk(p0[2], p0[3]);
    pk_.u[2] = cvtpk(p1[0], p1[1]);
    pk_.u[3] = cvtpk(p1[2], p1[3]);
    return pk_.v;
}

// ---------------- Flash attention: K/V register reuse across 2 q-row groups ------
// Round-7 evidence: attn pinned at 85us while VALUBusy dropped 49->39% -> L2-BW
// bound (~25 TB/s of K/V reads, 72% of the 34.5 ceiling; 4 rg-waves re-read the
// same K/V). Fix: each rg-wave owns 32 q rows (groups lo/hi); one K/V load
// feeds 2 QK^T + 2 PV -> L2 traffic halves. Block = 128-row q-tile, paired
// {p, 15-p} for exact balance; grid (8, B*H) = 512 blocks, XCD remap keeps
// 8 bh per XCD (KV L2-resident). jg = w>>2 splits j-range (stride 64);
// fixed-max softmax stays additive so jg partials combine as o+=o', l+=l'.
__global__ __launch_bounds__(512, 4) void attn_kernel(const u16* __restrict__ Q,
        const u16* __restrict__ K, const u16* __restrict__ Vt,
        const float* __restrict__ rel, u16* __restrict__ y) {
    const int id = blockIdx.x + 8 * blockIdx.y;     // 0..511
    const int xcd = id & 7;
    const int idx = id >> 3;                        // 0..63
    const int bh = xcd * 8 + (idx & 7);             // 8 bh per XCD
    const int p = idx >> 3;                         // 0..7
    const int h = bh & (NH - 1);
    const int b = bh >> 4;
    const int tid = threadIdx.x;
    const int w = tid >> 6, lane = tid & 63;
    const int rg = w & 3, jg = w >> 2;
    const int quad = lane >> 4, l16 = lane & 15;

    __shared__ alignas(16) float rel_s[NREL];
    __shared__ alignas(16) f32x4 cb[4][2][5][64];   // 40 KB combine buffer
    __shared__ alignas(16) u16 st_s[4][1024];       // 8 KB y-store staging
    if (tid < NREL) rel_s[tid] = rel[h * NREL + tid];
    __syncthreads();
    const float r128 = rel_s[128];

    const u16* Qh = Q  + (size_t)bh * TSEQ * DH;    // frag-major regions
    const u16* Kh = K  + (size_t)bh * TSEQ * DH;
    const u16* Vh = Vt + (size_t)bh * TSEQ * DH;

    bf16x8 ones;
#pragma unroll
    for (int j = 0; j < 8; j++) ones[j] = (short)0x3F80;

    for (int ti = 0; ti < 2; ti++) {
        const int qt = ti ? (15 - p) : p;
        const int lo = qt * 128 + rg * 32;          // lower 16-row group base
        const int hi = lo + 16;                     // upper 16-row group base
        const int gqL = lo + l16, gqH = hi + l16;
        const u16* qb = Qh + (size_t)(lo >> 4) * 1024 + lane * 8;
        const bf16x8 qf0L = *(const bf16x8*)(qb);
        const bf16x8 qf1L = *(const bf16x8*)(qb + 512);
        const bf16x8 qf0H = *(const bf16x8*)(qb + 1024);
        const bf16x8 qf1H = *(const bf16x8*)(qb + 1536);

        f32x4 o0[4], o1[4];
#pragma unroll
        for (int i = 0; i < 4; i++) {
            o0[i] = (f32x4){0.f, 0.f, 0.f, 0.f};
            o1[i] = (f32x4){0.f, 0.f, 0.f, 0.f};
        }
        f32x4 l0 = (f32x4){0.f, 0.f, 0.f, 0.f};
        f32x4 l1 = (f32x4){0.f, 0.f, 0.f, 0.f};

        for (int j0 = jg * 32; j0 < lo + 32; j0 += 64) {
            const u16* kb = Kh + (size_t)(j0 >> 5) * 2048 + lane * 8;
            const bf16x8 k00 = *(const bf16x8*)(kb);
            const bf16x8 k01 = *(const bf16x8*)(kb + 512);
            const bf16x8 k10 = *(const bf16x8*)(kb + 1024);
            const bf16x8 k11 = *(const bf16x8*)(kb + 1536);
            const bool doLo = j0 < hi;              // wave-uniform: lo group live

            f32x4 sH0 = (f32x4){0.f, 0.f, 0.f, 0.f};
            f32x4 sH1 = (f32x4){0.f, 0.f, 0.f, 0.f};
            sH0 = __builtin_amdgcn_mfma_f32_16x16x32_bf16(k00, qf0H, sH0, 0, 0, 0);
            sH0 = __builtin_amdgcn_mfma_f32_16x16x32_bf16(k01, qf1H, sH0, 0, 0, 0);
            sH1 = __builtin_amdgcn_mfma_f32_16x16x32_bf16(k10, qf0H, sH1, 0, 0, 0);
            sH1 = __builtin_amdgcn_mfma_f32_16x16x32_bf16(k11, qf1H, sH1, 0, 0, 0);
            f32x4 sL0 = (f32x4){0.f, 0.f, 0.f, 0.f};
            f32x4 sL1 = (f32x4){0.f, 0.f, 0.f, 0.f};
            if (doLo) {
                sL0 = __builtin_amdgcn_mfma_f32_16x16x32_bf16(k00, qf0L, sL0, 0, 0, 0);
                sL0 = __builtin_amdgcn_mfma_f32_16x16x32_bf16(k01, qf1L, sL0, 0, 0, 0);
                sL1 = __builtin_amdgcn_mfma_f32_16x16x32_bf16(k10, qf0L, sL1, 0, 0, 0);
                sL1 = __builtin_amdgcn_mfma_f32_16x16x32_bf16(k11, qf1L, sL1, 0, 0, 0);
            }

            const bf16x8 pfH = sm_pack(sH0, sH1, gqH - j0 - 8 * quad,
                                       j0 + 159 < hi, rel_s, r128);
            bf16x8 pfL = pfH;   // dummy init; only used under doLo
            if (doLo)
                pfL = sm_pack(sL0, sL1, gqL - j0 - 8 * quad,
                              j0 + 159 < lo, rel_s, r128);

            const u16* vb = Vh + (size_t)(j0 >> 5) * 2048 + lane * 8;
            bf16x8 vf[4];
#pragma unroll
            for (int dt = 0; dt < 4; dt++)
                vf[dt] = *(const bf16x8*)(vb + dt * 512);
#pragma unroll
            for (int dt = 0; dt < 4; dt++)
                o1[dt] = __builtin_amdgcn_mfma_f32_16x16x32_bf16(pfH, vf[dt], o1[dt], 0, 0, 0);
            l1 = __builtin_amdgcn_mfma_f32_16x16x32_bf16(pfH, ones, l1, 0, 0, 0);
            if (doLo) {
#pragma unroll
                for (int dt = 0; dt < 4; dt++)
                    o0[dt] = __builtin_amdgcn_mfma_f32_16x16x32_bf16(pfL, vf[dt], o0[dt], 0, 0, 0);
                l0 = __builtin_amdgcn_mfma_f32_16x16x32_bf16(pfL, ones, l0, 0, 0, 0);
            }
        }

        if (jg == 1) {
#pragma unroll
            for (int dt = 0; dt < 4; dt++) {
                cb[rg][0][dt][lane] = o0[dt];
                cb[rg][1][dt][lane] = o1[dt];
            }
            cb[rg][0][4][lane] = l0;
            cb[rg][1][4][lane] = l1;
        }
        __syncthreads();
        if (jg == 0) {
#define FINISH(G, OG, LG, BASE) do {                                         \
            _Pragma("unroll")                                                \
            for (int dt = 0; dt < 4; dt++) {                                 \
                const f32x4 op = cb[rg][G][dt][lane];                        \
                OG[dt].x += op.x; OG[dt].y += op.y;                          \
                OG[dt].z += op.z; OG[dt].w += op.w;                          \
            }                                                                \
            const f32x4 lp = cb[rg][G][4][lane];                             \
            LG.x += lp.x; LG.y += lp.y; LG.z += lp.z; LG.w += lp.w;          \
            float inv[4];                                                    \
            _Pragma("unroll")                                                \
            for (int r = 0; r < 4; r++) inv[r] = 1.0f / LG[r];               \
            u16* st = st_s[rg];                                              \
            _Pragma("unroll")                                                \
            for (int dt = 0; dt < 4; dt++)                                   \
                _Pragma("unroll")                                            \
                for (int r = 0; r < 4; r++)                                  \
                    st[(quad * 4 + r) * 64 + dt * 16 + l16] =                \
                        f2b(OG[dt][r] * inv[r]);                             \
            _Pragma("unroll")                                                \
            for (int ps = 0; ps < 2; ps++) {                                 \
                const bf16x8 vv = *(const bf16x8*)(st + ps * 512 + lane * 8);\
                const int row = (BASE) + ps * 8 + (lane >> 3);               \
                *(bf16x8*)(y + ((size_t)(b * TSEQ + row)) * DM + h * DH      \
                           + (lane & 7) * 8) = vv;                           \
            }                                                                \
        } while (0)
            FINISH(0, o0, l0, lo);
            FINISH(1, o1, l1, hi);
#undef FINISH
        }
        __syncthreads();   // cb/st reused by next ti
    }
}

extern "C" void kernel_launch(void* const* d_in, const int* in_sizes, int n_in,
                              void* d_out, int out_size, void* d_ws, size_t ws_size,
                              hipStream_t stream) {
    const float* x   = (const float*)d_in[0];
    const float* Wq  = (const float*)d_in[1];
    const float* Wk  = (const float*)d_in[2];
    const float* Wv  = (const float*)d_in[3];
    const float* Wo  = (const float*)d_in[4];
    const float* rel = (const float*)d_in[5];
    const float* gam = (const float*)d_in[6];
    const float* bet = (const float*)d_in[7];
    u16* ws = (u16*)d_ws;
    const size_t SZ = (size_t)BATCH * TSEQ * DM;
    const size_t need_bytes = 4 * SZ * sizeof(u16);

    if (n_in != 8) {
        fill_kernel<<<4096, 256, 0, stream>>>((float*)d_out, out_size, 8000.0f);
        return;
    }
    if (ws_size < need_bytes) {
        fill_kernel<<<4096, 256, 0, stream>>>((float*)d_out, out_size, 9500.0f);
        return;
    }

    u16* xn = ws;             // [B*T, D] normalized input (bf16)
    u16* Qb = ws + SZ;        // bf16 frag-major Q (pre-scaled by 1/8 via Wq)
    u16* Kb = ws + 2 * SZ;    // bf16 frag-major K
    u16* Vb = ws + 3 * SZ;    // bf16 frag-major V
    u16* y  = xn;             // attention output reuses xn region

    // bf16 weight scratch lives in d_out (33.5 MB; only written by the final
    // GEMM): [0,2MB) Wq*0.125, [2,4MB) Wk, [4,6MB) Wv. Wo-bf16 goes into Qb
    // after attn frees it.
    u16* wscr = (u16*)d_out;
    const int W4 = (DM * DM) / 4;   // 2^18 vec4 per matrix

    ln_kernel<<<BATCH * TSEQ, 256, 0, stream>>>(x, gam, bet, xn);
    cvt3_kernel<<<3 * W4 / 256, 256, 0, stream>>>(Wq, Wk, Wv, wscr);
    gemm_qkv<<<dim3(BATCH * TSEQ / BM, 24), 256, 0, stream>>>(xn, wscr, Qb, Kb, Vb);
    attn_kernel<<<dim3(8, BATCH * NH), 512, 0, stream>>>(Qb, Kb, Vb, rel, y);
    cvt1_kernel<<<W4 / 256, 256, 0, stream>>>(Wo, Qb, W4);   // Qb free after attn
    gemm_wo<<<dim3(BATCH * TSEQ / BM, DM / BN), 256, 0, stream>>>(y, Qb, x, (float*)d_out);
}

// Round 9
// 256.894 us; speedup vs baseline: 1.7739x; 1.0335x over previous
//
#include <hip/hip_runtime.h>
#include <math.h>

#define TSEQ 2048
#define BATCH 4
#define NH 16
#define DH 64
#define DM 1024
#define NREL 129
#define NEGBIG (-1.0e30f)
#define FIXMAX 8.0f

typedef unsigned short u16;
typedef unsigned int u32;
typedef __attribute__((ext_vector_type(8))) short bf16x8;
typedef __attribute__((ext_vector_type(4))) float f32x4;
typedef __attribute__((ext_vector_type(4))) unsigned short u16x4;

typedef __attribute__((address_space(3))) void lds_void;
typedef const __attribute__((address_space(1))) void g_void;

__device__ inline u16 f2b(float f) {
    union { float f; u32 i; } c; c.f = f;
    u32 x = c.i;
    return (u16)((x + 0x7fffu + ((x >> 16) & 1u)) >> 16);
}

// packed RNE f32->bf16 pair: D.lo = bf16(lo), D.hi = bf16(hi).
// Bit-identical to f2b for positive normal/zero inputs (both RNE).
__device__ inline u32 cvtpk(float lo, float hi) {
    u32 r;
    asm("v_cvt_pk_bf16_f32 %0, %1, %2" : "=v"(r) : "v"(lo), "v"(hi));
    return r;
}

__global__ __launch_bounds__(256) void fill_kernel(float* __restrict__ out, int n, float v) {
    for (int i = blockIdx.x * 256 + threadIdx.x; i < n; i += gridDim.x * 256)
        out[i] = v;
}

// ---------------- LayerNorm: fp32 in -> bf16 out, one block per row ----------------
__global__ __launch_bounds__(256) void ln_kernel(const float* __restrict__ x,
        const float* __restrict__ gamma, const float* __restrict__ beta,
        u16* __restrict__ xn) {
    const int row = blockIdx.x;
    const int tid = threadIdx.x;
    const float* xr = x + (size_t)row * DM;
    f32x4 xv = *(const f32x4*)(xr + tid * 4);
    float s = xv.x + xv.y + xv.z + xv.w;
    float s2 = xv.x*xv.x + xv.y*xv.y + xv.z*xv.z + xv.w*xv.w;
#pragma unroll
    for (int off = 32; off > 0; off >>= 1) {
        s  += __shfl_down(s, off, 64);
        s2 += __shfl_down(s2, off, 64);
    }
    __shared__ alignas(16) float red[8];
    const int wv = tid >> 6, ln = tid & 63;
    if (ln == 0) { red[wv] = s; red[4 + wv] = s2; }
    __syncthreads();
    s  = red[0] + red[1] + red[2] + red[3];
    s2 = red[4] + red[5] + red[6] + red[7];
    const float mu = s * (1.0f / DM);
    float var = s2 * (1.0f / DM) - mu * mu;
    var = var > 0.0f ? var : 0.0f;
    const float rstd = rsqrtf(var + 1e-5f);
    f32x4 gv = *(const f32x4*)(gamma + tid * 4);
    f32x4 bv = *(const f32x4*)(beta + tid * 4);
    u16x4 ov;
    ov.x = f2b((xv.x - mu) * rstd * gv.x + bv.x);
    ov.y = f2b((xv.y - mu) * rstd * gv.y + bv.y);
    ov.z = f2b((xv.z - mu) * rstd * gv.z + bv.z);
    ov.w = f2b((xv.w - mu) * rstd * gv.w + bv.w);
    *(u16x4*)(xn + (size_t)row * DM + tid * 4) = ov;
}

// ---------------- Weight conversion: fp32 -> bf16, done ONCE ----------------
__global__ __launch_bounds__(256) void cvt3_kernel(const float* __restrict__ a,
        const float* __restrict__ b, const float* __restrict__ c,
        u16* __restrict__ dst) {
    const int i = blockIdx.x * 256 + threadIdx.x;      // vec4 index, [0, 3*2^18)
    const int m = i >> 18;                              // 2^18 vec4 per 1024x1024
    const int j = i & 0x3FFFF;
    const float* src = m == 0 ? a : (m == 1 ? b : c);
    const float scale = m == 0 ? 0.125f : 1.0f;
    f32x4 v = *(const f32x4*)(src + (size_t)j * 4);
    u16x4 o;
    o.x = f2b(v.x * scale); o.y = f2b(v.y * scale);
    o.z = f2b(v.z * scale); o.w = f2b(v.w * scale);
    *(u16x4*)(dst + (size_t)i * 4) = o;
}

__global__ __launch_bounds__(256) void cvt1_kernel(const float* __restrict__ src,
        u16* __restrict__ dst, int n4) {
    const int i = blockIdx.x * 256 + threadIdx.x;
    if (i >= n4) return;
    f32x4 v = *(const f32x4*)(src + (size_t)i * 4);
    u16x4 o;
    o.x = f2b(v.x); o.y = f2b(v.y); o.z = f2b(v.z); o.w = f2b(v.w);
    *(u16x4*)(dst + (size_t)i * 4) = o;
}

// ---------------- GEMM: 128x128 tile, BK=32, 2-phase double-buffered LDS --------
// LDS slot-swizzle (T2, both-sides per rule #21): the [128][32]u16 tile has a
// 64B row stride -> ds_read_b128 at (row*32 + quad*8) was an 8-WAY bank
// conflict (round-8: SQ_LDS_BANK_CONFLICT=7.6M). Keep the global_load_lds LDS
// dest linear; pre-swizzle the GLOBAL source slot (scol ^= (lane>>3)&3) and
// read with the matching XOR (slot = quad ^ ((l16>>1)&3)). Residual 2-way
// aliasing is free (m136).
#define BM 128
#define BN 128
#define BK 32

// Fragment-major layouts for attention operands (pure permutations of Q/K/V).
// Qf: per bh, per 16-q block: 2 chunks (d 0-31, 32-63) of 512 u16;
//     (t,d) -> chunk (d>>5), slot = ((d>>3)&3)*16 + (t&15), e = d&7.
// Kf: per bh, per 32-j block: 4 chunks {k00,k01,k10,k11}:
//     jr=j&31: hi=(jr>>2)&1, lk=(jr&3)|((jr>>3)<<2); chunk = hi*2 + (d>>5);
//     slot = ((d>>3)&3)*16 + lk, e = d&7.
// Vf: per bh, per 32-j block: 4 chunks dt=d>>4:
//     slot = ((t>>3)&3)*16 + (d&15), e = t&7.
__global__ __launch_bounds__(256) void gemm_qkv(const u16* __restrict__ A,
        const u16* __restrict__ W3, u16* __restrict__ Qb, u16* __restrict__ Kb,
        u16* __restrict__ Vb) {
    __shared__ alignas(16) u16 sh[16384];   // A dbuf [2][4096] + B dbuf [2][4096]
    const int id = blockIdx.x + 64 * blockIdx.y;   // 0..1535
    const int xcd = id & 7;
    const int k = id >> 3;                          // 0..191
    const int xv = xcd * 8 + (k & 7);               // m-panel: 8 per XCD
    const int yv = k >> 3;                          // 0..23 (mat, n-panel)
    const int m0 = xv * BM;
    const int mat = yv >> 3;
    const int n0 = (yv & 7) * BN;
    const u16* Wb = W3 + (size_t)mat * DM * DM;
    const int tid = threadIdx.x;
    const int w = tid >> 6;
    const int lane = tid & 63;
    const int quad = lane >> 4, l16 = lane & 15;
    const int wr = (w >> 1) * 64;
    const int wc = (w & 1) * 64;

    const int c0 = w * 2;
    const int srow = c0 * 16 + (lane >> 2);
    // pre-swizzled global source slot: LDS (row,s) gets logical slot s^sigma(row),
    // sigma(row) = (row>>1)&3 = (lane>>3)&3 on the write side
    const int scol = (((lane & 3) ^ ((lane >> 3) & 3))) * 8;
    const u16* ag = A  + (size_t)(m0 + srow) * DM + scol;
    const u16* bg = Wb + (size_t)(n0 + srow) * DM + scol;
    u16* asw = sh + c0 * 512;           // + buf*4096
    u16* bsw = sh + 8192 + c0 * 512;    // + buf*4096
    // matching read swizzle: logical slot quad lives at quad ^ ((l16>>1)&3)
    const int sx = (quad ^ ((l16 >> 1) & 3)) * 8;

    f32x4 acc[4][4];
#pragma unroll
    for (int i = 0; i < 4; i++)
#pragma unroll
        for (int j = 0; j < 4; j++) acc[i][j] = (f32x4){0.f, 0.f, 0.f, 0.f};

#define QKV_STAGE(buf, kk) do { \
    __builtin_amdgcn_global_load_lds((g_void*)(ag + (kk)),            (lds_void*)(asw + (buf)*4096),       16, 0, 0); \
    __builtin_amdgcn_global_load_lds((g_void*)(ag + (kk) + 16 * DM),  (lds_void*)(asw + (buf)*4096 + 512), 16, 0, 0); \
    __builtin_amdgcn_global_load_lds((g_void*)(bg + (kk)),            (lds_void*)(bsw + (buf)*4096),       16, 0, 0); \
    __builtin_amdgcn_global_load_lds((g_void*)(bg + (kk) + 16 * DM),  (lds_void*)(bsw + (buf)*4096 + 512), 16, 0, 0); \
} while (0)

    QKV_STAGE(0, 0);
    __syncthreads();
    for (int k0 = 0; k0 < DM; k0 += BK) {
        const int cur = (k0 >> 5) & 1;
        if (k0 + BK < DM) QKV_STAGE(cur ^ 1, k0 + BK);
        const u16* Ac = sh + cur * 4096;
        const u16* Bc = sh + 8192 + cur * 4096;
        bf16x8 af[4], bfr[4];
#pragma unroll
        for (int mt = 0; mt < 4; mt++)
            af[mt] = *(const bf16x8*)(Ac + (wr + mt * 16 + l16) * BK + sx);
#pragma unroll
        for (int nt = 0; nt < 4; nt++)
            bfr[nt] = *(const bf16x8*)(Bc + (wc + nt * 16 + l16) * BK + sx);
#pragma unroll
        for (int mt = 0; mt < 4; mt++)
#pragma unroll
            for (int nt = 0; nt < 4; nt++)
                acc[mt][nt] = __builtin_amdgcn_mfma_f32_16x16x32_bf16(af[mt], bfr[nt], acc[mt][nt], 0, 0, 0);
        __syncthreads();   // drains next-tile loads (after MFMA cover) + read fence
    }
#undef QKV_STAGE

    // ---- Epilogue: per-wave 4KB LDS staging -> coalesced 1KB chunk stores ----
    u16* outb = mat == 0 ? Qb : (mat == 1 ? Kb : Vb);
    const size_t bh = (size_t)(m0 >> 11) * NH + ((n0 + wc) >> 6);
    const int tq = (m0 & 2047) + wr;                // quadrant first row in batch
    u16* stage = sh + w * 2048;                     // per-wave 4KB (buffers dead now)

#pragma unroll
    for (int p = 0; p < 2; p++) {
#pragma unroll
        for (int mt = 0; mt < 4; mt++) {
#pragma unroll
            for (int ntl = 0; ntl < 2; ntl++) {
                const int nt = p * 2 + ntl;
#pragma unroll
                for (int r = 0; r < 4; r++) {
                    const u16 val = f2b(acc[mt][nt][r]);
                    int a;
                    if (mat == 0) {
                        a = mt * 512
                          + ((ntl * 2 + (l16 >> 3)) * 16 + quad * 4 + r) * 8 + (l16 & 7);
                    } else if (mat == 1) {
                        a = ((mt >> 1) * 2 + (quad & 1)) * 512
                          + ((ntl * 2 + (l16 >> 3)) * 16 + (quad >> 1) * 4 + (mt & 1) * 8 + r) * 8
                          + (l16 & 7);
                    } else {
                        a = ((mt >> 1) * 2 + ntl) * 512
                          + (((mt * 2 + (quad >> 1)) & 3) * 16 + l16) * 8
                          + (quad & 1) * 4 + r;
                    }
                    stage[a] = val;
                }
            }
        }
        // same-wave LDS write->read (short-typed reads alias u16 stores)
#pragma unroll
        for (int c = 0; c < 4; c++) {
            const bf16x8 vv = *(const bf16x8*)(stage + c * 512 + lane * 8);
            size_t gc;
            if (mat == 0)      gc = (bh * 128 + (tq >> 4) + c) * 2 + p;
            else if (mat == 1) gc = (bh * 64 + (tq >> 5) + (c >> 1)) * 4 + (c & 1) * 2 + p;
            else               gc = (bh * 64 + (tq >> 5) + (c >> 1)) * 4 + p * 2 + (c & 1);
            *(bf16x8*)(outb + gc * 512 + lane * 8) = vv;
        }
    }
}

// Output projection + residual: out = y @ Wo^T + x0 (fp32 out).
// Same XCD remap; same 2-phase double-buffered schedule; same LDS slot-swizzle.
__global__ __launch_bounds__(256) void gemm_wo(const u16* __restrict__ A,
        const u16* __restrict__ Wb, const float* __restrict__ X0,
        float* __restrict__ out) {
    __shared__ alignas(16) u16 sh[16384];
    const int id = blockIdx.x + 64 * blockIdx.y;   // 0..511
    const int xcd = id & 7;
    const int k = id >> 3;                          // 0..63
    const int m0 = (xcd * 8 + (k & 7)) * BM;
    const int n0 = (k >> 3) * BN;
    const int tid = threadIdx.x;
    const int w = tid >> 6;
    const int lane = tid & 63;
    const int quad = lane >> 4, l16 = lane & 15;
    const int wr = (w >> 1) * 64;
    const int wc = (w & 1) * 64;

    const int c0 = w * 2;
    const int srow = c0 * 16 + (lane >> 2);
    const int scol = (((lane & 3) ^ ((lane >> 3) & 3))) * 8;
    const u16* ag = A  + (size_t)(m0 + srow) * DM + scol;
    const u16* bg = Wb + (size_t)(n0 + srow) * DM + scol;
    u16* asw = sh + c0 * 512;
    u16* bsw = sh + 8192 + c0 * 512;
    const int sx = (quad ^ ((l16 >> 1) & 3)) * 8;

    f32x4 acc[4][4];
#pragma unroll
    for (int i = 0; i < 4; i++)
#pragma unroll
        for (int j = 0; j < 4; j++) acc[i][j] = (f32x4){0.f, 0.f, 0.f, 0.f};

#define WO_STAGE(buf, kk) do { \
    __builtin_amdgcn_global_load_lds((g_void*)(ag + (kk)),            (lds_void*)(asw + (buf)*4096),       16, 0, 0); \
    __builtin_amdgcn_global_load_lds((g_void*)(ag + (kk) + 16 * DM),  (lds_void*)(asw + (buf)*4096 + 512), 16, 0, 0); \
    __builtin_amdgcn_global_load_lds((g_void*)(bg + (kk)),            (lds_void*)(bsw + (buf)*4096),       16, 0, 0); \
    __builtin_amdgcn_global_load_lds((g_void*)(bg + (kk) + 16 * DM),  (lds_void*)(bsw + (buf)*4096 + 512), 16, 0, 0); \
} while (0)

    WO_STAGE(0, 0);
    __syncthreads();
    for (int k0 = 0; k0 < DM; k0 += BK) {
        const int cur = (k0 >> 5) & 1;
        if (k0 + BK < DM) WO_STAGE(cur ^ 1, k0 + BK);
        const u16* Ac = sh + cur * 4096;
        const u16* Bc = sh + 8192 + cur * 4096;
        bf16x8 af[4], bfr[4];
#pragma unroll
        for (int mt = 0; mt < 4; mt++)
            af[mt] = *(const bf16x8*)(Ac + (wr + mt * 16 + l16) * BK + sx);
#pragma unroll
        for (int nt = 0; nt < 4; nt++)
            bfr[nt] = *(const bf16x8*)(Bc + (wc + nt * 16 + l16) * BK + sx);
#pragma unroll
        for (int mt = 0; mt < 4; mt++)
#pragma unroll
            for (int nt = 0; nt < 4; nt++)
                acc[mt][nt] = __builtin_amdgcn_mfma_f32_16x16x32_bf16(af[mt], bfr[nt], acc[mt][nt], 0, 0, 0);
        __syncthreads();
    }
#undef WO_STAGE

#pragma unroll
    for (int mt = 0; mt < 4; mt++) {
#pragma unroll
        for (int nt = 0; nt < 4; nt++) {
#pragma unroll
            for (int r = 0; r < 4; r++) {
                const int row = m0 + wr + mt * 16 + quad * 4 + r;
                const int col = n0 + wc + nt * 16 + l16;
                const size_t idx = (size_t)row * DM + col;
                out[idx] = acc[mt][nt][r] + X0[idx];
            }
        }
    }
}

// softmax + bf16-pack for one 16-row group. s0[r]: j = j0+8*quad+r; s1[r]: j += 4.
// dq = gq - j0 - 8*quad; fast <=> all dists in tile > 128.
__device__ inline bf16x8 sm_pack(f32x4 s0, f32x4 s1, int dq, bool fast,
                                 const float* rel_s, float r128) {
    float p0[4], p1[4];
    if (fast) {
#pragma unroll
        for (int r = 0; r < 4; r++) {
            p0[r] = __expf(s0[r] + (r128 - FIXMAX));
            p1[r] = __expf(s1[r] + (r128 - FIXMAX));
        }
    } else {
#pragma unroll
        for (int r = 0; r < 4; r++) {
            const int d0 = dq - r;
            const int d1 = dq - 4 - r;
            const int c0 = d0 < 0 ? 0 : (d0 > 128 ? 128 : d0);
            const int c1 = d1 < 0 ? 0 : (d1 > 128 ? 128 : d1);
            float sv0 = s0[r] + rel_s[c0];
            float sv1 = s1[r] + rel_s[c1];
            sv0 = d0 >= 0 ? sv0 : NEGBIG;
            sv1 = d1 >= 0 ? sv1 : NEGBIG;
            p0[r] = __expf(sv0 - FIXMAX);   // masked -> exp(-huge) = 0
            p1[r] = __expf(sv1 - FIXMAX);
        }
    }
    union { u32 u[4]; bf16x8 v; } pk_;      // A-frag: k = quad*8 + e
    pk_.u[0] = cvtpk(p0[0], p0[1]);
    pk_.u[1] = cvtpk(p0[2], p0[3]);
    pk_.u[2] = cvtpk(p1[0], p1[1]);
    pk_.u[3] = cvtpk(p1[2], p1[3]);
    return pk_.v;
}

// ---------------- Flash attention: K/V register reuse across 2 q-row groups ------
// Each rg-wave owns 32 q rows (groups lo/hi); one K/V load feeds 2 QK^T + 2 PV
// -> L2 traffic halved vs round 7. Block = 128-row q-tile, paired {p, 15-p};
// grid (8, B*H) = 512 blocks, XCD remap keeps 8 bh per XCD (KV L2-resident).
// jg = w>>2 splits j-range (stride 64); fixed-max softmax stays additive so
// jg partials combine as o+=o', l+=l'.
__global__ __launch_bounds__(512, 4) void attn_kernel(const u16* __restrict__ Q,
        const u16* __restrict__ K, const u16* __restrict__ Vt,
        const float* __restrict__ rel, u16* __restrict__ y) {
    const int id = blockIdx.x + 8 * blockIdx.y;     // 0..511
    const int xcd = id & 7;
    const int idx = id >> 3;                        // 0..63
    const int bh = xcd * 8 + (idx & 7);             // 8 bh per XCD
    const int p = idx >> 3;                         // 0..7
    const int h = bh & (NH - 1);
    const int b = bh >> 4;
    const int tid = threadIdx.x;
    const int w = tid >> 6, lane = tid & 63;
    const int rg = w & 3, jg = w >> 2;
    const int quad = lane >> 4, l16 = lane & 15;

    __shared__ alignas(16) float rel_s[NREL];
    __shared__ alignas(16) f32x4 cb[4][2][5][64];   // 40 KB combine buffer
    __shared__ alignas(16) u16 st_s[4][1024];       // 8 KB y-store staging
    if (tid < NREL) rel_s[tid] = rel[h * NREL + tid];
    __syncthreads();
    const float r128 = rel_s[128];

    const u16* Qh = Q  + (size_t)bh * TSEQ * DH;    // frag-major regions
    const u16* Kh = K  + (size_t)bh * TSEQ * DH;
    const u16* Vh = Vt + (size_t)bh * TSEQ * DH;

    bf16x8 ones;
#pragma unroll
    for (int j = 0; j < 8; j++) ones[j] = (short)0x3F80;

    for (int ti = 0; ti < 2; ti++) {
        const int qt = ti ? (15 - p) : p;
        const int lo = qt * 128 + rg * 32;          // lower 16-row group base
        const int hi = lo + 16;                     // upper 16-row group base
        const int gqL = lo + l16, gqH = hi + l16;
        const u16* qb = Qh + (size_t)(lo >> 4) * 1024 + lane * 8;
        const bf16x8 qf0L = *(const bf16x8*)(qb);
        const bf16x8 qf1L = *(const bf16x8*)(qb + 512);
        const bf16x8 qf0H = *(const bf16x8*)(qb + 1024);
        const bf16x8 qf1H = *(const bf16x8*)(qb + 1536);

        f32x4 o0[4], o1[4];
#pragma unroll
        for (int i = 0; i < 4; i++) {
            o0[i] = (f32x4){0.f, 0.f, 0.f, 0.f};
            o1[i] = (f32x4){0.f, 0.f, 0.f, 0.f};
        }
        f32x4 l0 = (f32x4){0.f, 0.f, 0.f, 0.f};
        f32x4 l1 = (f32x4){0.f, 0.f, 0.f, 0.f};

        for (int j0 = jg * 32; j0 < lo + 32; j0 += 64) {
            const u16* kb = Kh + (size_t)(j0 >> 5) * 2048 + lane * 8;
            const bf16x8 k00 = *(const bf16x8*)(kb);
            const bf16x8 k01 = *(const bf16x8*)(kb + 512);
            const bf16x8 k10 = *(const bf16x8*)(kb + 1024);
            const bf16x8 k11 = *(const bf16x8*)(kb + 1536);
            const bool doLo = j0 < hi;              // wave-uniform: lo group live

            f32x4 sH0 = (f32x4){0.f, 0.f, 0.f, 0.f};
            f32x4 sH1 = (f32x4){0.f, 0.f, 0.f, 0.f};
            sH0 = __builtin_amdgcn_mfma_f32_16x16x32_bf16(k00, qf0H, sH0, 0, 0, 0);
            sH0 = __builtin_amdgcn_mfma_f32_16x16x32_bf16(k01, qf1H, sH0, 0, 0, 0);
            sH1 = __builtin_amdgcn_mfma_f32_16x16x32_bf16(k10, qf0H, sH1, 0, 0, 0);
            sH1 = __builtin_amdgcn_mfma_f32_16x16x32_bf16(k11, qf1H, sH1, 0, 0, 0);
            f32x4 sL0 = (f32x4){0.f, 0.f, 0.f, 0.f};
            f32x4 sL1 = (f32x4){0.f, 0.f, 0.f, 0.f};
            if (doLo) {
                sL0 = __builtin_amdgcn_mfma_f32_16x16x32_bf16(k00, qf0L, sL0, 0, 0, 0);
                sL0 = __builtin_amdgcn_mfma_f32_16x16x32_bf16(k01, qf1L, sL0, 0, 0, 0);
                sL1 = __builtin_amdgcn_mfma_f32_16x16x32_bf16(k10, qf0L, sL1, 0, 0, 0);
                sL1 = __builtin_amdgcn_mfma_f32_16x16x32_bf16(k11, qf1L, sL1, 0, 0, 0);
            }

            const bf16x8 pfH = sm_pack(sH0, sH1, gqH - j0 - 8 * quad,
                                       j0 + 159 < hi, rel_s, r128);
            bf16x8 pfL = pfH;   // dummy init; only used under doLo
            if (doLo)
                pfL = sm_pack(sL0, sL1, gqL - j0 - 8 * quad,
                              j0 + 159 < lo, rel_s, r128);

            const u16* vb = Vh + (size_t)(j0 >> 5) * 2048 + lane * 8;
            bf16x8 vf[4];
#pragma unroll
            for (int dt = 0; dt < 4; dt++)
                vf[dt] = *(const bf16x8*)(vb + dt * 512);
#pragma unroll
            for (int dt = 0; dt < 4; dt++)
                o1[dt] = __builtin_amdgcn_mfma_f32_16x16x32_bf16(pfH, vf[dt], o1[dt], 0, 0, 0);
            l1 = __builtin_amdgcn_mfma_f32_16x16x32_bf16(pfH, ones, l1, 0, 0, 0);
            if (doLo) {
#pragma unroll
                for (int dt = 0; dt < 4; dt++)
                    o0[dt] = __builtin_amdgcn_mfma_f32_16x16x32_bf16(pfL, vf[dt], o0[dt], 0, 0, 0);
                l0 = __builtin_amdgcn_mfma_f32_16x16x32_bf16(pfL, ones, l0, 0, 0, 0);
            }
        }

        if (jg == 1) {
#pragma unroll
            for (int dt = 0; dt < 4; dt++) {
                cb[rg][0][dt][lane] = o0[dt];
                cb[rg][1][dt][lane] = o1[dt];
            }
            cb[rg][0][4][lane] = l0;
            cb[rg][1][4][lane] = l1;
        }
        __syncthreads();
        if (jg == 0) {
#define FINISH(G, OG, LG, BASE) do {                                         \
            _Pragma("unroll")                                                \
            for (int dt = 0; dt < 4; dt++) {                                 \
                const f32x4 op = cb[rg][G][dt][lane];                        \
                OG[dt].x += op.x; OG[dt].y += op.y;                          \
                OG[dt].z += op.z; OG[dt].w += op.w;                          \
            }                                                                \
            const f32x4 lp = cb[rg][G][4][lane];                             \
            LG.x += lp.x; LG.y += lp.y; LG.z += lp.z; LG.w += lp.w;          \
            float inv[4];                                                    \
            _Pragma("unroll")                                                \
            for (int r = 0; r < 4; r++) inv[r] = 1.0f / LG[r];               \
            u16* st = st_s[rg];                                              \
            _Pragma("unroll")                                                \
            for (int dt = 0; dt < 4; dt++)                                   \
                _Pragma("unroll")                                            \
                for (int r = 0; r < 4; r++)                                  \
                    st[(quad * 4 + r) * 64 + dt * 16 + l16] =                \
                        f2b(OG[dt][r] * inv[r]);                             \
            _Pragma("unroll")                                                \
            for (int ps = 0; ps < 2; ps++) {                                 \
                const bf16x8 vv = *(const bf16x8*)(st + ps * 512 + lane * 8);\
                const int row = (BASE) + ps * 8 + (lane >> 3);               \
                *(bf16x8*)(y + ((size_t)(b * TSEQ + row)) * DM + h * DH      \
                           + (lane & 7) * 8) = vv;                           \
            }                                                                \
        } while (0)
            FINISH(0, o0, l0, lo);
            FINISH(1, o1, l1, hi);
#undef FINISH
        }
        __syncthreads();   // cb/st reused by next ti
    }
}

extern "C" void kernel_launch(void* const* d_in, const int* in_sizes, int n_in,
                              void* d_out, int out_size, void* d_ws, size_t ws_size,
                              hipStream_t stream) {
    const float* x   = (const float*)d_in[0];
    const float* Wq  = (const float*)d_in[1];
    const float* Wk  = (const float*)d_in[2];
    const float* Wv  = (const float*)d_in[3];
    const float* Wo  = (const float*)d_in[4];
    const float* rel = (const float*)d_in[5];
    const float* gam = (const float*)d_in[6];
    const float* bet = (const float*)d_in[7];
    u16* ws = (u16*)d_ws;
    const size_t SZ = (size_t)BATCH * TSEQ * DM;
    const size_t need_bytes = 4 * SZ * sizeof(u16);

    if (n_in != 8) {
        fill_kernel<<<4096, 256, 0, stream>>>((float*)d_out, out_size, 8000.0f);
        return;
    }
    if (ws_size < need_bytes) {
        fill_kernel<<<4096, 256, 0, stream>>>((float*)d_out, out_size, 9500.0f);
        return;
    }

    u16* xn = ws;             // [B*T, D] normalized input (bf16)
    u16* Qb = ws + SZ;        // bf16 frag-major Q (pre-scaled by 1/8 via Wq)
    u16* Kb = ws + 2 * SZ;    // bf16 frag-major K
    u16* Vb = ws + 3 * SZ;    // bf16 frag-major V
    u16* y  = xn;             // attention output reuses xn region

    // bf16 weight scratch lives in d_out (33.5 MB; only written by the final
    // GEMM): [0,2MB) Wq*0.125, [2,4MB) Wk, [4,6MB) Wv. Wo-bf16 goes into Qb
    // after attn frees it.
    u16* wscr = (u16*)d_out;
    const int W4 = (DM * DM) / 4;   // 2^18 vec4 per matrix

    ln_kernel<<<BATCH * TSEQ, 256, 0, stream>>>(x, gam, bet, xn);
    cvt3_kernel<<<3 * W4 / 256, 256, 0, stream>>>(Wq, Wk, Wv, wscr);
    gemm_qkv<<<dim3(BATCH * TSEQ / BM, 24), 256, 0, stream>>>(xn, wscr, Qb, Kb, Vb);
    attn_kernel<<<dim3(8, BATCH * NH), 512, 0, stream>>>(Qb, Kb, Vb, rel, y);
    cvt1_kernel<<<W4 / 256, 256, 0, stream>>>(Wo, Qb, W4);   // Qb free after attn
    gemm_wo<<<dim3(BATCH * TSEQ / BM, DM / BN), 256, 0, stream>>>(y, Qb, x, (float*)d_out);
}